// Round 8
// baseline (489.600 us; speedup 1.0000x reference)
//
#include <hip/hip_runtime.h>
#include <math.h>

#define EPS_F 1e-5f

typedef __attribute__((ext_vector_type(8))) short short8;
typedef __attribute__((ext_vector_type(4))) float f32x4;
typedef __attribute__((ext_vector_type(8))) unsigned short ushort8;
typedef __attribute__((ext_vector_type(4))) unsigned short ushort4v;
typedef __attribute__((ext_vector_type(4))) int int4v;

__device__ __forceinline__ int reflect512(int v) {
    v = v < 0 ? -v : v;
    return v >= 512 ? 1022 - v : v;
}

// XCD-aware block swizzle: consecutive LOGICAL tiles share input rows; map
// them to the same XCD (HW round-robins launched id % 8) so halo/row
// re-reads hit the XCD-local L2 instead of L3. Bijective when n % 8 == 0.
__device__ __forceinline__ int xcd_swz(int L, int n) {
    return (L & 7) * (n >> 3) + (L >> 3);
}

// float -> bf16 bits, round-to-nearest-even
__device__ __forceinline__ ushort f2bf(float f) {
    union { float f; unsigned u; } v; v.f = f;
    unsigned r = v.u + 0x7FFFu + ((v.u >> 16) & 1u);
    return (ushort)(r >> 16);
}
__device__ __forceinline__ float bf2f(ushort u) {
    union { unsigned u; float f; } v; v.u = (unsigned)u << 16;
    return v.f;
}

// 2x f32 -> packed bf16 (RNE) in ONE instruction (no builtin on gfx950).
__device__ __forceinline__ unsigned cvt_pk_bf16(float lo, float hi) {
    unsigned r;
    asm("v_cvt_pk_bf16_f32 %0, %1, %2" : "=v"(r) : "v"(lo), "v"(hi));
    return r;
}

// tanh via hardware exp2 + rcp: ~7 VALU ops vs libm's ~25+.
__device__ __forceinline__ float fast_tanh(float x) {
    float cx = fminf(fmaxf(x, -9.f), 9.f);
    float e  = __builtin_amdgcn_exp2f(cx * 2.8853900817779268f); // 2*log2(e)
    return (e - 1.f) * __builtin_amdgcn_rcpf(e + 1.f);
}

// ---------------------------------------------------------------------------
// Weight prep, single fused dispatch. (unchanged from r7)
// ---------------------------------------------------------------------------
template<int CIN, int COUT, bool DEC>
__device__ __forceinline__ void wp_mid(
    const float* __restrict__ w, ushort* __restrict__ dst, int i)
{
    constexpr int CIP = ((CIN + 31) / 32) * 32;
    int ci = i % CIP;
    int oc = (i / CIP) % COUT;
    int t  = i / (CIP * COUT);
    float x = 0.f;
    if (ci < CIN)
        x = DEC ? w[((size_t)ci * COUT + oc) * 9 + t]
                : w[((size_t)oc * CIN + ci) * 9 + t];
    dst[i] = f2bf(x);
}

// L1 conv 16->32: chunk c covers taps (2c, 2c+1); chunk 4 pads tap 9 with 0.
__device__ __forceinline__ void wp_l1(
    const float* __restrict__ w, ushort* __restrict__ dst, int i)
{
    int k  = i & 31;
    int oc = (i >> 5) & 31;
    int c  = i >> 10;
    int tapsel = k >> 4, ci = k & 15;
    int t = 2 * c + tapsel;
    float x = (t < 9) ? w[((size_t)oc * 16 + ci) * 9 + t] : 0.f;
    dst[i] = f2bf(x);
}

template<bool L9>
__device__ __forceinline__ void wp_7(
    const float* __restrict__ w, ushort* __restrict__ dst, int i)
{
    int j   = i & 7;
    int oc  = (i >> 3) & 15;
    int kqe = (i >> 7) & 3;
    int cn  = i >> 9;
    float x = 0.f;
    if (L9) {
        // chunk cn = ty*4 + q; k = kqe*8+j; tapsel=k>>4; ci=k&15; tx=2q+tapsel.
        int k = kqe * 8 + j;
        int tapsel = k >> 4, ci = k & 15;
        int ty = cn >> 2, q = cn & 3;
        int tx = 2 * q + tapsel;
        if (tx < 7 && oc < 3 && ty < 7)
            x = w[((size_t)oc * 16 + ci) * 49 + ty * 7 + tx];
    } else {
        // chunk cn = ty (0..6); k = kqe*8+j; dx=k>>2; ci=k&3.
        int k = kqe * 8 + j;
        int dx = k >> 2, ci = k & 3;
        if (dx < 7 && ci < 3)
            x = w[((size_t)oc * 3 + ci) * 49 + cn * 7 + dx];
    }
    dst[i] = f2bf(x);
}

struct WprepArgs {
    const float* w[10];
    ushort* d[10];   // d[0]=L0 pack, d[1..8]=mid (d[1]=L1 pack), d[9]=L9 pack
};

__global__ __launch_bounds__(256) void wprep_all(WprepArgs a)
{
    int bi = blockIdx.x;
    int t  = threadIdx.x;
    if      (bi < 20)   wp_l1(a.w[1], a.d[1], (bi        ) * 256 + t);
    else if (bi < 92)   wp_mid<32,  64,  false>(a.w[2], a.d[2], (bi - 20   ) * 256 + t);
    else if (bi < 380)  wp_mid<64,  128, false>(a.w[3], a.d[3], (bi - 92   ) * 256 + t);
    else if (bi < 1532) wp_mid<128, 256, false>(a.w[4], a.d[4], (bi - 380  ) * 256 + t);
    else if (bi < 2684) wp_mid<256, 128, true >(a.w[5], a.d[5], (bi - 1532 ) * 256 + t);
    else if (bi < 2972) wp_mid<128, 64,  true >(a.w[6], a.d[6], (bi - 2684 ) * 256 + t);
    else if (bi < 3044) wp_mid<64,  32,  true >(a.w[7], a.d[7], (bi - 2972 ) * 256 + t);
    else if (bi < 3062) wp_mid<32,  16,  true >(a.w[8], a.d[8], (bi - 3044 ) * 256 + t);
    else if (bi < 3076) wp_7<false>(a.w[0], a.d[0], (bi - 3062) * 256 + t);
    else                wp_7<true >(a.w[9], a.d[9], (bi - 3076) * 256 + t);
}

// ---------------------------------------------------------------------------
// MFMA implicit-GEMM conv (MODE 0: 3x3 s2 p1) / deconv (MODE 1: k3 s2 p1 op1).
// (unchanged from r7; used for L2..L8)
// ---------------------------------------------------------------------------
template<int CIN, int COUT, int WIN, int MODE, int NWN, int MSUB, int RT, int CT>
__global__ __launch_bounds__(256) void mfconv(
    const ushort* __restrict__ in, const ushort* __restrict__ wbf,
    const float* __restrict__ bias, ushort* __restrict__ out,
    const float* __restrict__ stats_in, float invHWin,
    float* __restrict__ stats_out)
{
    constexpr int HWIN = WIN * WIN;
    constexpr int WOUT = (MODE == 0) ? (WIN / 2) : (WIN * 2);
    constexpr int HWOUT = WOUT * WOUT;
    constexpr int NMG = 4 / NWN;
    constexpr int NOC = NWN * 16;
    constexpr int M = NMG * MSUB * 16;
    static_assert(M == RT * CT, "tile mismatch");
    constexpr int SPAN = (MODE == 0) ? WOUT : WIN;
    constexpr int XC = SPAN / CT, YC = SPAN / RT;
    constexpr int NG = COUT / NOC;
    constexpr int NR = (MODE == 0) ? (2 * RT + 1) : (RT + 1);
    constexpr int NCO = (MODE == 0) ? (2 * CT + 1) : (CT + 1);
    constexpr int NPIX = NR * NCO;
    constexpr int CIP = ((CIN + 31) / 32) * 32;
    constexpr int NQ = (MODE == 0) ? 1 : 4;
    constexpr int LPW = 36;               // A-tile LDS row stride (ushorts)
    constexpr int NPOUT = (MODE == 0 ? 1 : 4) * M;
    constexpr int NOCP = NOC + 8;         // epilogue LDS row stride

    constexpr int TDY[9] = {1,1,1,0,0,0,0,0,0};
    constexpr int TDX[9] = {1,0,0,1,0,0,1,0,0};
    constexpr int TQ [9] = {3,2,3,1,0,1,3,2,3};

    extern __shared__ ushort sa[];        // max(NPIX*36, NPOUT*NOCP)
    __shared__ float mrall[CIP][2];
    __shared__ float sred[4][16][2];

    const int tid = threadIdx.x;
    const int lane = tid & 63, wv = tid >> 6;
    const int ln = lane & 15, kq = lane >> 4;
    const int wn = wv % NWN, wm = wv / NWN;
    const int grp = tid & 3;              // fixed channel-octet per thread

    int bi = xcd_swz(blockIdx.x, gridDim.x);
    const int xc = bi % XC; bi /= XC;
    const int yc = bi % YC; bi /= YC;
    const int g  = bi % NG;
    const int b  = bi / NG;

    const int ocg = g * NOC + wn * 16 + ln;
    const float b0 = bias[ocg];
    f32x4 acc[NQ][MSUB];
    #pragma unroll
    for (int q = 0; q < NQ; q++)
        #pragma unroll
        for (int s = 0; s < MSUB; s++)
            acc[q][s] = (f32x4){b0, b0, b0, b0};

    for (int e = tid; e < CIP; e += 256) {
        float m = 0.f, r = 0.f;
        if (e < CIN) {
            int c = b * CIN + e;
            float s1 = stats_in[2 * c], s2 = stats_in[2 * c + 1];
            m = s1 * invHWin;
            r = rsqrtf(fmaf(s2, invHWin, -m * m) + EPS_F);
        }
        mrall[e][0] = m; mrall[e][1] = r;
    }

    const ushort* inb = in + (size_t)b * HWIN * CIN;

    for (int c0 = 0; c0 < CIP; c0 += 32) {
        __syncthreads();   // prev tile consumed; mrall visible on iter 0
        const int ch0 = c0 + 8 * grp;
        float m8[8], r8[8];
        #pragma unroll
        for (int j = 0; j < 8; j++) { m8[j] = mrall[ch0 + j][0]; r8[j] = mrall[ch0 + j][1]; }
        for (int pix = tid >> 2; pix < NPIX; pix += 64) {
            int pr = pix / NCO, pc = pix - pr * NCO;
            int gy, gx;
            if (MODE == 0) { gy = 2 * (yc * RT) - 1 + pr; gx = 2 * (xc * CT) - 1 + pc; }
            else           { gy = yc * RT + pr;           gx = xc * CT + pc; }
            ushort8 pk;
            #pragma unroll
            for (int j = 0; j < 8; j++) pk[j] = 0;
            if ((unsigned)gy < (unsigned)WIN && (unsigned)gx < (unsigned)WIN && ch0 < CIN) {
                ushort8 raw = *(const ushort8*)(inb + (size_t)(gy * WIN + gx) * CIN + ch0);
                #pragma unroll
                for (int j = 0; j < 8; j++) {
                    float x = bf2f(raw[j]);
                    pk[j] = f2bf(fmaxf((x - m8[j]) * r8[j], 0.f));
                }
            }
            *(ushort8*)&sa[pix * LPW + grp * 8] = pk;
        }
        __syncthreads();
        #pragma unroll
        for (int t = 0; t < 9; t++) {
            short8 bfr = *(const short8*)&wbf[((size_t)t * COUT + ocg) * CIP + c0 + kq * 8];
            #pragma unroll
            for (int s = 0; s < MSUB; s++) {
                const int mb = wm * MSUB * 16 + s * 16;
                const int r = mb / CT, cb = mb % CT;
                int pix;
                if (MODE == 0) pix = (t / 3 + 2 * r) * NCO + 2 * (cb + ln) + t % 3;
                else           pix = (TDY[t] + r) * NCO + cb + ln + TDX[t];
                short8 afr = *(const short8*)&sa[pix * LPW + kq * 8];
                int qd = (MODE == 0) ? 0 : TQ[t];
                acc[qd][s] = __builtin_amdgcn_mfma_f32_16x16x32_bf16(afr, bfr, acc[qd][s], 0, 0, 0);
            }
        }
    }

    // ---- stats partials (registers only) ----
    float s1 = 0.f, s2 = 0.f;
    #pragma unroll
    for (int q = 0; q < NQ; q++)
        #pragma unroll
        for (int s = 0; s < MSUB; s++)
            #pragma unroll
            for (int rg = 0; rg < 4; rg++) {
                float v = acc[q][s][rg];
                s1 += v; s2 = fmaf(v, v, s2);
            }
    s1 += __shfl_xor(s1, 16); s2 += __shfl_xor(s2, 16);
    s1 += __shfl_xor(s1, 32); s2 += __shfl_xor(s2, 32);
    if (lane < 16) { sred[wv][lane][0] = s1; sred[wv][lane][1] = s2; }

    // ---- assemble outputs in LDS (reuse sa) ----
    __syncthreads();                       // all waves done reading sa
    const int ocl = wn * 16 + ln;
    if (MODE == 0) {
        #pragma unroll
        for (int s = 0; s < MSUB; s++)
            #pragma unroll
            for (int rg = 0; rg < 4; rg++) {
                const int m = wm * MSUB * 16 + s * 16 + kq * 4 + rg;
                sa[m * NOCP + ocl] = f2bf(acc[0][s][rg]);
            }
    } else {
        #pragma unroll
        for (int q = 0; q < 4; q++) {
            const int dy = q >> 1, dx = q & 1;
            #pragma unroll
            for (int s = 0; s < MSUB; s++)
                #pragma unroll
                for (int rg = 0; rg < 4; rg++) {
                    const int m = wm * MSUB * 16 + s * 16 + kq * 4 + rg;
                    const int r = m / CT, c = m % CT;
                    const int lp = (2 * r + dy) * (2 * CT) + 2 * c + dx;
                    sa[lp * NOCP + ocl] = f2bf(acc[q][s][rg]);
                }
        }
    }
    __syncthreads();

    // ---- dense coalesced stores ----
    ushort* ob = out + (size_t)b * HWOUT * COUT + g * NOC;
    for (int e = tid; e < (NPOUT * NOC) / 8; e += 256) {
        int u = e * 8;
        int lp = u / NOC, co = u % NOC;
        int gp;
        if (MODE == 0) {
            int r = lp / CT, c = lp % CT;
            gp = (yc * RT + r) * WOUT + xc * CT + c;
        } else {
            int r2 = lp / (2 * CT), x2 = lp % (2 * CT);
            gp = (2 * (yc * RT) + r2) * WOUT + 2 * (xc * CT) + x2;
        }
        *(ushort8*)&ob[(size_t)gp * COUT + co] = *(const ushort8*)&sa[lp * NOCP + co];
    }

    if (tid < NOC) {
        int wnn = tid >> 4, oc = tid & 15;
        float t1 = 0.f, t2 = 0.f;
        #pragma unroll
        for (int k = 0; k < NMG; k++) {
            t1 += sred[wnn + k * NWN][oc][0];
            t2 += sred[wnn + k * NWN][oc][1];
        }
        int cix = b * COUT + g * NOC + wnn * 16 + oc;
        atomicAdd(&stats_out[2 * cix],     t1);
        atomicAdd(&stats_out[2 * cix + 1], t2);
    }
}

// ---------------------------------------------------------------------------
// L1 dedicated: conv 3x3 s2 p1, 16->32 @512->256. (unchanged from r7)
// ---------------------------------------------------------------------------
__global__ __launch_bounds__(256) void mfconv_l1(
    const ushort* __restrict__ in, const ushort* __restrict__ wbf,
    const float* __restrict__ bias, ushort* __restrict__ out,
    const float* __restrict__ stats_in, float invHWin,
    float* __restrict__ stats_out)
{
    constexpr int WIN = 512, HWIN = WIN * WIN;
    constexpr int WOUT = 256, HWOUT = WOUT * WOUT;
    constexpr int COUT = 32, RT = 4, CT = 32;
    constexpr int NCO = 65, NPIX = 585;     // 9 x 65 halo
    constexpr int NOCP = 40;                // 32 oc + 8 pad

    extern __shared__ ushort sa[];          // max(585*16, 128*40) = 9360 us
    __shared__ float mrall[16][2];
    __shared__ float sred[4][16][2];

    const int tid = threadIdx.x;
    const int lane = tid & 63, wv = tid >> 6;
    const int ln = lane & 15, kq = lane >> 4;
    const int wn = wv & 1, wm = wv >> 1;

    int bi = xcd_swz(blockIdx.x, gridDim.x);
    const int xc = bi & 7;
    const int yc = (bi >> 3) & 63;
    const int b  = bi >> 9;

    const int ocg = wn * 16 + ln;
    const float b0 = bias[ocg];
    f32x4 acc[4];
    #pragma unroll
    for (int s = 0; s < 4; s++) acc[s] = (f32x4){b0, b0, b0, b0};

    if (tid < 16) {
        int c = b * 16 + tid;
        float s1 = stats_in[2 * c], s2 = stats_in[2 * c + 1];
        float m = s1 * invHWin;
        mrall[tid][0] = m;
        mrall[tid][1] = rsqrtf(fmaf(s2, invHWin, -m * m) + EPS_F);
    }

    // Issue all staging loads up front (latency hides under mrall + barrier).
    const int grp = tid & 1, p0 = tid >> 1;
    const ushort* inb = in + (size_t)b * HWIN * 16 + grp * 8;
    ushort8 rw[5];
    bool ok[5];
    #pragma unroll
    for (int i = 0; i < 5; i++) {
        int pix = p0 + i * 128;
        int pr = pix / NCO, pc = pix - pr * NCO;
        int gy = 2 * (yc * RT) - 1 + pr;
        int gx = 2 * (xc * CT) - 1 + pc;
        ok[i] = (pix < NPIX) && ((unsigned)gy < (unsigned)WIN)
                             && ((unsigned)gx < (unsigned)WIN);
        if (ok[i])
            rw[i] = *(const ushort8*)(inb + (size_t)(gy * WIN + gx) * 16);
    }
    __syncthreads();     // mrall ready

    float m8[8], r8[8];
    #pragma unroll
    for (int j = 0; j < 8; j++) {
        m8[j] = mrall[grp * 8 + j][0];
        r8[j] = mrall[grp * 8 + j][1];
    }
    #pragma unroll
    for (int i = 0; i < 5; i++) {
        int pix = p0 + i * 128;
        if (pix < NPIX) {
            ushort8 pk;
            #pragma unroll
            for (int j = 0; j < 8; j++) pk[j] = 0;
            if (ok[i]) {
                #pragma unroll
                for (int j = 0; j < 8; j++) {
                    float x = bf2f(rw[i][j]);
                    pk[j] = f2bf(fmaxf((x - m8[j]) * r8[j], 0.f));
                }
            }
            int ep = (pix * 16 + grp * 8) ^ (((pix >> 2) & 1) << 3);
            *(ushort8*)&sa[ep] = pk;
        }
    }
    __syncthreads();

    // 5 K-chunks; lane's tap = 2c + (kq>>1); ch-octet = kq&1.
    const int tp = kq >> 1, off8 = (kq & 1) * 8;
    #pragma unroll
    for (int c = 0; c < 5; c++) {
        short8 bfr = *(const short8*)&wbf[(size_t)(c * COUT + ocg) * 32 + kq * 8];
        int t = 2 * c + tp; t = t > 8 ? 8 : t;   // c=4,tp=1: weights are 0
        const int ty = t / 3, tx = t - 3 * ty;
        #pragma unroll
        for (int s = 0; s < 4; s++) {
            const int mb = wm * 64 + s * 16;
            const int r = mb >> 5, cb = mb & 31;
            int px = (ty + 2 * r) * NCO + 2 * (cb + ln) + tx;
            int ep = (px * 16 + off8) ^ (((px >> 2) & 1) << 3);
            short8 afr = *(const short8*)&sa[ep];
            acc[s] = __builtin_amdgcn_mfma_f32_16x16x32_bf16(afr, bfr, acc[s], 0, 0, 0);
        }
    }

    // ---- stats partials ----
    float s1 = 0.f, s2 = 0.f;
    #pragma unroll
    for (int s = 0; s < 4; s++)
        #pragma unroll
        for (int rg = 0; rg < 4; rg++) {
            float v = acc[s][rg];
            s1 += v; s2 = fmaf(v, v, s2);
        }
    s1 += __shfl_xor(s1, 16); s2 += __shfl_xor(s2, 16);
    s1 += __shfl_xor(s1, 32); s2 += __shfl_xor(s2, 32);
    if (lane < 16) { sred[wv][lane][0] = s1; sred[wv][lane][1] = s2; }

    // ---- assemble + dense stores ----
    __syncthreads();
    const int ocl = wn * 16 + ln;
    #pragma unroll
    for (int s = 0; s < 4; s++)
        #pragma unroll
        for (int rg = 0; rg < 4; rg++) {
            const int m = wm * 64 + s * 16 + kq * 4 + rg;
            sa[m * NOCP + ocl] = f2bf(acc[s][rg]);
        }
    __syncthreads();
    ushort* ob = out + (size_t)b * HWOUT * COUT;
    for (int e = tid; e < 512; e += 256) {
        int u = e * 8;
        int lp = u >> 5, co = u & 31;
        int r = lp >> 5, c = lp & 31;
        int gp = (yc * RT + r) * WOUT + xc * CT + c;
        *(ushort8*)&ob[(size_t)gp * COUT + co] = *(const ushort8*)&sa[lp * NOCP + co];
    }
    if (tid < 32) {
        int wnn = tid >> 4, oc = tid & 15;
        float t1 = 0.f, t2 = 0.f;
        #pragma unroll
        for (int k = 0; k < 2; k++) {
            t1 += sred[wnn + k * 2][oc][0];
            t2 += sred[wnn + k * 2][oc][1];
        }
        int cix = b * COUT + wnn * 16 + oc;
        atomicAdd(&stats_out[2 * cix],     t1);
        atomicAdd(&stats_out[2 * cix + 1], t2);
    }
}

// ---------------------------------------------------------------------------
// L0: 7x7 reflect conv @512 via MFMA (BFIN=false path only; unchanged r7).
// ---------------------------------------------------------------------------
template<bool BFIN>
__global__ __launch_bounds__(256, 4) void conv7x(
    const float* __restrict__ inf,
    const ushort* __restrict__ wpk, const float* __restrict__ bias,
    ushort* __restrict__ out, float* __restrict__ stats_out)
{
    constexpr int W = 512, HW = 512 * 512;
    constexpr int HCOL = 70;
    constexpr int NPIXH = 980;
    constexpr int SASZ = 12288;

    __shared__ ushort sa[SASZ];
    __shared__ float sred[4][16][2];

    const int tid = threadIdx.x;
    const int lane = tid & 63, wv = tid >> 6;
    const int ln = lane & 15, kq = lane >> 4;

    int bi = xcd_swz(blockIdx.x, gridDim.x);
    const int xc = bi & 7;
    const int yr = (bi >> 3) & 63;
    const int b  = bi >> 9;
    const int y0 = yr * 8, x0 = xc * 64;

    {
        const float* p0 = inf + (size_t)b * 3 * HW;
        for (int pix = tid; pix < NPIXH; pix += 256) {
            int pr = pix / HCOL, pc = pix - pr * HCOL;
            int gy = reflect512(y0 - 3 + pr);
            int gx = reflect512(x0 - 3 + pc);
            const float* p = p0 + gy * W + gx;
            ushort4v pk;
            pk[0] = f2bf(p[0]); pk[1] = f2bf(p[HW]);
            pk[2] = f2bf(p[2 * (size_t)HW]); pk[3] = 0;
            *(ushort4v*)&sa[pix * 4] = pk;
        }
        if (tid < 16) sa[980 * 4 + tid] = 0;    // zero pad (dx=7 tail reads)
    }
    __syncthreads();

    const float b0 = bias[ln];
    f32x4 acc[8];
    #pragma unroll
    for (int s = 0; s < 8; s++) acc[s] = (f32x4){b0, b0, b0, b0};

    {
        // Wave owns rows 0..7, cols c0..c0+15. A-frag = 2 adjacent px x 4ch.
        const int c0 = wv * 16;
        const int abase = (c0 + ln + 2 * kq) * 4;
        const ushort* wp0 = wpk + ((size_t)kq * 16 + ln) * 8;
        short8 bw[7];
        #pragma unroll
        for (int ty = 0; ty < 7; ty++)
            bw[ty] = *(const short8*)(wp0 + (size_t)ty * 512);
        #pragma unroll
        for (int R = 0; R < 14; R++) {
            short8 afr = *(const short8*)&sa[abase + R * (HCOL * 4)];
            #pragma unroll
            for (int ty = 0; ty < 7; ty++) {
                const int s = R - ty;
                if (s >= 0 && s < 8)
                    acc[s] = __builtin_amdgcn_mfma_f32_16x16x32_bf16(afr, bw[ty], acc[s], 0, 0, 0);
            }
        }
    }

    // stats partials first (registers), then LDS-assembled NHWC store.
    float s1 = 0.f, s2 = 0.f;
    #pragma unroll
    for (int s = 0; s < 8; s++)
        #pragma unroll
        for (int rg = 0; rg < 4; rg++) {
            float v = acc[s][rg];
            s1 += v; s2 = fmaf(v, v, s2);
        }
    s1 += __shfl_xor(s1, 16); s2 += __shfl_xor(s2, 16);
    s1 += __shfl_xor(s1, 32); s2 += __shfl_xor(s2, 32);
    if (lane < 16) { sred[wv][lane][0] = s1; sred[wv][lane][1] = s2; }

    __syncthreads();   // A-tile reads done; reuse sa as [512][24]
    #pragma unroll
    for (int s = 0; s < 8; s++)
        #pragma unroll
        for (int rg = 0; rg < 4; rg++) {
            int m = s * 64 + wv * 16 + kq * 4 + rg;
            sa[m * 24 + ln] = f2bf(acc[s][rg]);
        }
    __syncthreads();
    ushort* ob = out + (size_t)b * HW * 16;
    for (int e = tid; e < 1024; e += 256) {
        int u = e * 8;
        int lp = u >> 4, co = u & 15;
        int gp = (y0 + (lp >> 6)) * W + x0 + (lp & 63);
        *(ushort8*)&ob[(size_t)gp * 16 + co] = *(const ushort8*)&sa[lp * 24 + co];
    }
    if (tid < 16) {
        float t1 = 0.f, t2 = 0.f;
        #pragma unroll
        for (int k = 0; k < 4; k++) { t1 += sred[k][tid][0]; t2 += sred[k][tid][1]; }
        int cix = b * 16 + tid;
        atomicAdd(&stats_out[2 * cix],     t1);
        atomicAdd(&stats_out[2 * cix + 1], t2);
    }
}

// ---------------------------------------------------------------------------
// L9 PERSISTENT: 7x7 16->3 @512 + norm + tanh + seg. 1024 blocks x 4 tiles.
// Double-buffered A-tile; per iter: issue loads(t+1) -> MFMA(t) [disjoint
// buffers, no barrier between] -> vmcnt+norm+write(t+1) -> sf epilogue
// (its 2 barriers double as the swap fences). Load latency hides under
// MFMA; barriers 4->2 per tile; segl flushed once per block.
// Tiles of one block: same y-band, consecutive xc (halo L2 reuse).
// LDS: 2x17.1KB bufs + 5KB sf + misc = ~40KB -> 4 blocks/CU.
// ---------------------------------------------------------------------------
__global__ __launch_bounds__(256, 4) void conv7x_l9p(
    const ushort* __restrict__ inb16, const ushort* __restrict__ wpk,
    const float* __restrict__ bias, const float* __restrict__ stats_in,
    float invHWin, const int* __restrict__ inst, float* __restrict__ segacc)
{
    constexpr int W = 512, HW = 512 * 512;
    constexpr int HCOL = 38, STR = 16;
    constexpr int SA1 = 8544;              // 532*16 + 32 pad

    __shared__ ushort sa[2][SA1];
    __shared__ float sf[1280];
    __shared__ float mr[16][2];
    __shared__ float segl[128];

    const int tid = threadIdx.x;
    const int lane = tid & 63, wv = tid >> 6;
    const int ln = lane & 15, kq = lane >> 4;

    const int L  = (blockIdx.x & 7) * 128 + (blockIdx.x >> 3);
    const int t0 = L * 4;
    const int b  = t0 >> 10;
    const int yr = (t0 >> 4) & 63;
    const int xcb = t0 & 15;
    const int y0 = yr * 8;

    const int h = tid & 1;
    const ushort* inbb = inb16 + (size_t)b * HW * 16 + 8 * h;
    const int* ib = inst + ((size_t)b << 18);

    ushort8 rw[5];

#define L9_ISSUE(X0) do {                                                   \
    _Pragma("unroll")                                                       \
    for (int i2 = 0; i2 < 5; i2++) {                                        \
        int pix = (tid >> 1) + i2 * 128;                                    \
        if (pix < 532) {                                                    \
            int pr = pix / HCOL, pc = pix - pr * HCOL;                      \
            int gy = reflect512(y0 - 3 + pr);                               \
            int gx = reflect512((X0) - 3 + pc);                             \
            rw[i2] = *(const ushort8*)(inbb + (size_t)(gy * W + gx) * 16);  \
        } } } while (0)

#define L9_WRITE(BUF) do {                                                  \
    _Pragma("unroll")                                                       \
    for (int i2 = 0; i2 < 5; i2++) {                                        \
        int pix = (tid >> 1) + i2 * 128;                                    \
        if (pix < 532) {                                                    \
            union { ushort8 us; unsigned u[4]; } P;                         \
            _Pragma("unroll")                                               \
            for (int q2 = 0; q2 < 4; q2++) {                                \
                float lo = fmaxf(fmaf(bf2f(rw[i2][2*q2]),   r8[2*q2],   nm8[2*q2]),   0.f); \
                float hi = fmaxf(fmaf(bf2f(rw[i2][2*q2+1]), r8[2*q2+1], nm8[2*q2+1]), 0.f); \
                P.u[q2] = cvt_pk_bf16(lo, hi);                              \
            }                                                               \
            *(ushort8*)&sa[BUF][pix * STR + 8 * h] = P.us;                  \
        } } } while (0)

    // ---- prologue: stage tile 0 ----
    L9_ISSUE(xcb * 32);
    if (tid < 16) {
        int c = b * 16 + tid;
        float s1 = stats_in[2 * c], s2 = stats_in[2 * c + 1];
        float m = s1 * invHWin;
        mr[tid][0] = m;
        mr[tid][1] = rsqrtf(fmaf(s2, invHWin, -m * m) + EPS_F);
    }
    if (tid < 128) segl[tid] = 0.f;
    if (tid >= 128 && tid < 160) {           // zero pads of both buffers
        sa[0][8512 + (tid - 128)] = 0;
        sa[1][8512 + (tid - 128)] = 0;
    }
    __syncthreads();                         // mr + pads ready

    float r8[8], nm8[8];
    #pragma unroll
    for (int j = 0; j < 8; j++) {
        r8[j]  = mr[8 * h + j][1];
        nm8[j] = -mr[8 * h + j][0] * r8[j];
    }
    L9_WRITE(0);
    int lab_next = ib[(y0 + (tid >> 5)) * W + xcb * 32 + (tid & 31)] & 31;
    __syncthreads();                         // buf0 ready

    const int wr = wv >> 1, wc = wv & 1;
    const int abase = ((wr * 4) * HCOL + wc * 16 + ln + (kq >> 1)) * STR + (kq & 1) * 8;
    const ushort* wp9 = wpk + ((size_t)kq * 16 + ln) * 8;
    const float b0 = (ln < 3) ? bias[ln] : 0.f;

    for (int it = 0; it < 4; ++it) {
        const int cur = it & 1;
        const int mylab = lab_next;
        // a: issue next tile's loads (consumed after MFMA -> latency hidden)
        if (it < 3) {
            L9_ISSUE((xcb + it + 1) * 32);
            lab_next = ib[(y0 + (tid >> 5)) * W + (xcb + it + 1) * 32 + (tid & 31)] & 31;
        }
        // b: MFMA from sa[cur]
        f32x4 acc[4];
        #pragma unroll
        for (int s = 0; s < 4; s++) acc[s] = (f32x4){b0, b0, b0, b0};
        #pragma unroll
        for (int q = 0; q < 4; q++) {
            short8 bw[7];
            #pragma unroll
            for (int ty = 0; ty < 7; ty++)
                bw[ty] = *(const short8*)(wp9 + (size_t)(ty * 4 + q) * 512);
            #pragma unroll
            for (int rr = 0; rr < 10; rr++) {
                short8 afr = *(const short8*)&sa[cur][abase + q * (2 * STR) + rr * (HCOL * STR)];
                #pragma unroll
                for (int ty = 0; ty < 7; ty++) {
                    const int s = rr - ty;
                    if (s >= 0 && s < 4)
                        acc[s] = __builtin_amdgcn_mfma_f32_16x16x32_bf16(afr, bw[ty], acc[s], 0, 0, 0);
                }
            }
        }
        // d: write next tile into the OTHER buffer (disjoint; no barrier yet)
        if (it < 3) L9_WRITE(cur ^ 1);
        // e: sf epilogue (barriers double as swap fences)
        if (ln < 3) {
            #pragma unroll
            for (int s = 0; s < 4; s++)
                #pragma unroll
                for (int rg = 0; rg < 4; rg++) {
                    int m = (wr * 4 + s) * 32 + wc * 16 + kq * 4 + rg;
                    sf[m * 5 + ln] = acc[s][rg];
                }
        }
        __syncthreads();
        atomicAdd(&segl[mylab * 4 + 0], fast_tanh(sf[tid * 5 + 0]));
        atomicAdd(&segl[mylab * 4 + 1], fast_tanh(sf[tid * 5 + 1]));
        atomicAdd(&segl[mylab * 4 + 2], fast_tanh(sf[tid * 5 + 2]));
        atomicAdd(&segl[mylab * 4 + 3], 1.f);
        __syncthreads();                     // sf reuse + buffer swap fence
    }

    if (tid < 128) {
        float v = segl[tid];
        if (v != 0.f)
            atomicAdd(&segacc[(blockIdx.x & 7) * 128 + tid], v);  // 8 shards
    }
#undef L9_ISSUE
#undef L9_WRITE
}

// ---------------------------------------------------------------------------
// Segment finalize (reduce 8 shards) + scatter (vectorized: 4 px/thread).
// ---------------------------------------------------------------------------
#define HW9 262144
__global__ void seg_final(const float* __restrict__ acc, float* __restrict__ means)
{
    int i = threadIdx.x;
    if (i < 96) {
        int s = i / 3, c = i - s * 3;
        float num = 0.f, den = 0.f;
        #pragma unroll
        for (int k = 0; k < 8; k++) {
            num += acc[k * 128 + s * 4 + c];
            den += acc[k * 128 + s * 4 + 3];
        }
        means[i] = num / fmaxf(den, 1.f);
    }
}

__global__ __launch_bounds__(256) void seg_scatter(
    const int* __restrict__ inst, const float* __restrict__ means,
    float* __restrict__ out)
{
    int p4 = blockIdx.x * 256 + threadIdx.x;   // 4-pixel unit
    int b  = p4 >> 16;                          // 65536 units per batch
    int r4 = (p4 & 65535) * 4;
    const int4v labs = *(const int4v*)(inst + ((size_t)b << 18) + r4);
    float* ob = out + (size_t)b * 3 * HW9 + r4;
    f32x4 o0, o1, o2;
    #pragma unroll
    for (int j = 0; j < 4; j++) {
        int l3 = (labs[j] & 31) * 3;
        o0[j] = means[l3]; o1[j] = means[l3 + 1]; o2[j] = means[l3 + 2];
    }
    *(f32x4*)(ob)           = o0;
    *(f32x4*)(ob + HW9)     = o1;
    *(f32x4*)(ob + 2 * HW9) = o2;
}

// ---------------------------------------------------------------------------
// Launch.
// ---------------------------------------------------------------------------
extern "C" void kernel_launch(void* const* d_in, const int* in_sizes, int n_in,
                              void* d_out, int out_size, void* d_ws, size_t ws_size,
                              hipStream_t stream)
{
    const float* x_in = (const float*)d_in[0];
    const int*   inst = (const int*)d_in[1];
    const float* W_[10];
    const float* Bs[10];
    for (int i = 0; i < 10; i++) {
        W_[i] = (const float*)d_in[2 + 2 * i];
        Bs[i] = (const float*)d_in[3 + 2 * i];
    }
    float* out = (float*)d_out;

    // NHWC bf16 activation ping-pong + fp32 stats + bf16 weights.
    ushort* Ab  = (ushort*)d_ws;            // 16,777,216 el
    ushort* Bb2 = Ab + (size_t)16777216;    //  8,388,608 el
    float*  st  = (float*)(Bb2 + (size_t)8388608);
    const int coff[9] = {0, 128, 384, 896, 1920, 3968, 4992, 5504, 5760};
    float* s_[9];
    for (int i = 0; i < 9; i++) s_[i] = st + coff[i];
    float* segacc = st + 5888;              // 8 shards x 128 = 1024 floats
    float* means  = st + 6912;              // 96 floats
    ushort* wb = (ushort*)(st + 8192);
    const size_t OW1 = 0, OW2 = 9216, OW3 = 27648, OW4 = 101376,
                 OW5 = 396288, OW6 = 691200, OW7 = 764928, OW8 = 783360;
    ushort* wb0 = wb + 790000;
    ushort* wb9 = wb0 + 6656;   // L9 pack: 28 chunks x 512 = 14336 ushorts

    hipMemsetAsync(st, 0, 6912 * sizeof(float), stream);

    WprepArgs wa;
    for (int i = 0; i < 10; i++) wa.w[i] = W_[i];
    wa.d[0] = wb0;
    wa.d[1] = wb + OW1; wa.d[2] = wb + OW2; wa.d[3] = wb + OW3; wa.d[4] = wb + OW4;
    wa.d[5] = wb + OW5; wa.d[6] = wb + OW6; wa.d[7] = wb + OW7; wa.d[8] = wb + OW8;
    wa.d[9] = wb9;
    wprep_all<<<dim3(3132), dim3(256), 0, stream>>>(wa);

    // L0: 7x7 3->16 @512, fp32 NCHW in -> NHWC bf16 out + stats. grid 2048.
    conv7x<false><<<dim3(2048), dim3(256), 0, stream>>>(
        x_in, wb0, Bs[0], Ab, s_[0]);

    // L1: conv 16->32 @512->256 (dedicated kernel, stride-16 A-tile). grid 2048.
    mfconv_l1<<<dim3(2048), dim3(256), 18720, stream>>>(
        Ab, wb + OW1, Bs[1], Bb2, s_[0], 1.f / 262144.f, s_[1]);

    // L2: conv 32->64 @256->128. grid 1024.
    mfconv<32, 64, 256, 0, 2, 4, 4, 32><<<dim3(1024), dim3(256), 42120, stream>>>(
        Bb2, wb + OW2, Bs[2], Ab, s_[1], 1.f / 65536.f, s_[2]);

    // L3: conv 64->128 @128->64. grid 512.
    mfconv<64, 128, 128, 0, 2, 4, 4, 32><<<dim3(512), dim3(256), 42120, stream>>>(
        Ab, wb + OW3, Bs[3], Bb2, s_[2], 1.f / 16384.f, s_[3]);

    // L4: conv 128->256 @64->32. grid 512.
    mfconv<128, 256, 64, 0, 2, 2, 2, 32><<<dim3(512), dim3(256), 23400, stream>>>(
        Bb2, wb + OW4, Bs[4], Ab, s_[3], 1.f / 4096.f, s_[4]);

    // L5: deconv 256->128 @32->64. grid 512. LDS 12288 (epilogue-sized).
    mfconv<256, 128, 32, 1, 1, 1, 2, 32><<<dim3(512), dim3(256), 12288, stream>>>(
        Ab, wb + OW5, Bs[5], Bb2, s_[4], 1.f / 1024.f, s_[5]);

    // L6: deconv 128->64 @64->128. grid 512. LDS 20480.
    mfconv<128, 64, 64, 1, 2, 2, 2, 32><<<dim3(512), dim3(256), 20480, stream>>>(
        Bb2, wb + OW6, Bs[6], Ab, s_[5], 1.f / 4096.f, s_[6]);

    // L7: deconv 64->32 @128->256. grid 1024. LDS 20480.
    mfconv<64, 32, 128, 1, 2, 2, 2, 32><<<dim3(1024), dim3(256), 20480, stream>>>(
        Ab, wb + OW7, Bs[7], Bb2, s_[6], 1.f / 16384.f, s_[7]);

    // L8: deconv 32->16 @256->512. M=128, grid 2048. LDS 24576.
    mfconv<32, 16, 256, 1, 1, 2, 2, 64><<<dim3(2048), dim3(256), 24576, stream>>>(
        Bb2, wb + OW8, Bs[8], Ab, s_[7], 1.f / 65536.f, s_[8]);

    // L9: persistent double-buffered. 1024 blocks x 4 tiles (8x32 each).
    conv7x_l9p<<<dim3(1024), dim3(256), 0, stream>>>(
        Ab, wb9, Bs[9], s_[8], 1.f / 262144.f, inst, segacc);

    seg_final<<<dim3(1), dim3(96), 0, stream>>>(segacc, means);
    seg_scatter<<<dim3(1024), dim3(256), 0, stream>>>(inst, means, out);
}

// Round 9
// 450.479 us; speedup vs baseline: 1.0868x; 1.0868x over previous
//
#include <hip/hip_runtime.h>
#include <math.h>

#define EPS_F 1e-5f

typedef __attribute__((ext_vector_type(8))) short short8;
typedef __attribute__((ext_vector_type(4))) float f32x4;
typedef __attribute__((ext_vector_type(8))) unsigned short ushort8;
typedef __attribute__((ext_vector_type(4))) unsigned short ushort4v;
typedef __attribute__((ext_vector_type(4))) int int4v;

__device__ __forceinline__ int reflect512(int v) {
    v = v < 0 ? -v : v;
    return v >= 512 ? 1022 - v : v;
}

// XCD-aware block swizzle: consecutive LOGICAL tiles share input rows; map
// them to the same XCD (HW round-robins launched id % 8) so halo/row
// re-reads hit the XCD-local L2 instead of L3. Bijective when n % 8 == 0.
__device__ __forceinline__ int xcd_swz(int L, int n) {
    return (L & 7) * (n >> 3) + (L >> 3);
}

// float -> bf16 bits, round-to-nearest-even
__device__ __forceinline__ ushort f2bf(float f) {
    union { float f; unsigned u; } v; v.f = f;
    unsigned r = v.u + 0x7FFFu + ((v.u >> 16) & 1u);
    return (ushort)(r >> 16);
}
__device__ __forceinline__ float bf2f(ushort u) {
    union { unsigned u; float f; } v; v.u = (unsigned)u << 16;
    return v.f;
}

// 2x f32 -> packed bf16 (RNE) in ONE instruction (no builtin on gfx950).
__device__ __forceinline__ unsigned cvt_pk_bf16(float lo, float hi) {
    unsigned r;
    asm("v_cvt_pk_bf16_f32 %0, %1, %2" : "=v"(r) : "v"(lo), "v"(hi));
    return r;
}

// tanh via hardware exp2 + rcp: ~7 VALU ops vs libm's ~25+.
__device__ __forceinline__ float fast_tanh(float x) {
    float cx = fminf(fmaxf(x, -9.f), 9.f);
    float e  = __builtin_amdgcn_exp2f(cx * 2.8853900817779268f); // 2*log2(e)
    return (e - 1.f) * __builtin_amdgcn_rcpf(e + 1.f);
}

// ---------------------------------------------------------------------------
// Weight prep, single fused dispatch. (unchanged from r8)
// ---------------------------------------------------------------------------
template<int CIN, int COUT, bool DEC>
__device__ __forceinline__ void wp_mid(
    const float* __restrict__ w, ushort* __restrict__ dst, int i)
{
    constexpr int CIP = ((CIN + 31) / 32) * 32;
    int ci = i % CIP;
    int oc = (i / CIP) % COUT;
    int t  = i / (CIP * COUT);
    float x = 0.f;
    if (ci < CIN)
        x = DEC ? w[((size_t)ci * COUT + oc) * 9 + t]
                : w[((size_t)oc * CIN + ci) * 9 + t];
    dst[i] = f2bf(x);
}

// L1 conv 16->32: chunk c covers taps (2c, 2c+1); chunk 4 pads tap 9 with 0.
__device__ __forceinline__ void wp_l1(
    const float* __restrict__ w, ushort* __restrict__ dst, int i)
{
    int k  = i & 31;
    int oc = (i >> 5) & 31;
    int c  = i >> 10;
    int tapsel = k >> 4, ci = k & 15;
    int t = 2 * c + tapsel;
    float x = (t < 9) ? w[((size_t)oc * 16 + ci) * 9 + t] : 0.f;
    dst[i] = f2bf(x);
}

template<bool L9>
__device__ __forceinline__ void wp_7(
    const float* __restrict__ w, ushort* __restrict__ dst, int i)
{
    int j   = i & 7;
    int oc  = (i >> 3) & 15;
    int kqe = (i >> 7) & 3;
    int cn  = i >> 9;
    float x = 0.f;
    if (L9) {
        // chunk cn = ty*4 + q; k = kqe*8+j; tapsel=k>>4; ci=k&15; tx=2q+tapsel.
        int k = kqe * 8 + j;
        int tapsel = k >> 4, ci = k & 15;
        int ty = cn >> 2, q = cn & 3;
        int tx = 2 * q + tapsel;
        if (tx < 7 && oc < 3 && ty < 7)
            x = w[((size_t)oc * 16 + ci) * 49 + ty * 7 + tx];
    } else {
        // chunk cn = ty (0..6); k = kqe*8+j; dx=k>>2; ci=k&3.
        int k = kqe * 8 + j;
        int dx = k >> 2, ci = k & 3;
        if (dx < 7 && ci < 3)
            x = w[((size_t)oc * 3 + ci) * 49 + cn * 7 + dx];
    }
    dst[i] = f2bf(x);
}

struct WprepArgs {
    const float* w[10];
    ushort* d[10];   // d[0]=L0 pack, d[1..8]=mid (d[1]=L1 pack), d[9]=L9 pack
};

__global__ __launch_bounds__(256) void wprep_all(WprepArgs a)
{
    int bi = blockIdx.x;
    int t  = threadIdx.x;
    if      (bi < 20)   wp_l1(a.w[1], a.d[1], (bi        ) * 256 + t);
    else if (bi < 92)   wp_mid<32,  64,  false>(a.w[2], a.d[2], (bi - 20   ) * 256 + t);
    else if (bi < 380)  wp_mid<64,  128, false>(a.w[3], a.d[3], (bi - 92   ) * 256 + t);
    else if (bi < 1532) wp_mid<128, 256, false>(a.w[4], a.d[4], (bi - 380  ) * 256 + t);
    else if (bi < 2684) wp_mid<256, 128, true >(a.w[5], a.d[5], (bi - 1532 ) * 256 + t);
    else if (bi < 2972) wp_mid<128, 64,  true >(a.w[6], a.d[6], (bi - 2684 ) * 256 + t);
    else if (bi < 3044) wp_mid<64,  32,  true >(a.w[7], a.d[7], (bi - 2972 ) * 256 + t);
    else if (bi < 3062) wp_mid<32,  16,  true >(a.w[8], a.d[8], (bi - 3044 ) * 256 + t);
    else if (bi < 3076) wp_7<false>(a.w[0], a.d[0], (bi - 3062) * 256 + t);
    else                wp_7<true >(a.w[9], a.d[9], (bi - 3076) * 256 + t);
}

// ---------------------------------------------------------------------------
// MFMA implicit-GEMM conv (MODE 0: 3x3 s2 p1) / deconv (MODE 1: k3 s2 p1 op1).
// (unchanged from r8; used for L2..L8)
// ---------------------------------------------------------------------------
template<int CIN, int COUT, int WIN, int MODE, int NWN, int MSUB, int RT, int CT>
__global__ __launch_bounds__(256) void mfconv(
    const ushort* __restrict__ in, const ushort* __restrict__ wbf,
    const float* __restrict__ bias, ushort* __restrict__ out,
    const float* __restrict__ stats_in, float invHWin,
    float* __restrict__ stats_out)
{
    constexpr int HWIN = WIN * WIN;
    constexpr int WOUT = (MODE == 0) ? (WIN / 2) : (WIN * 2);
    constexpr int HWOUT = WOUT * WOUT;
    constexpr int NMG = 4 / NWN;
    constexpr int NOC = NWN * 16;
    constexpr int M = NMG * MSUB * 16;
    static_assert(M == RT * CT, "tile mismatch");
    constexpr int SPAN = (MODE == 0) ? WOUT : WIN;
    constexpr int XC = SPAN / CT, YC = SPAN / RT;
    constexpr int NG = COUT / NOC;
    constexpr int NR = (MODE == 0) ? (2 * RT + 1) : (RT + 1);
    constexpr int NCO = (MODE == 0) ? (2 * CT + 1) : (CT + 1);
    constexpr int NPIX = NR * NCO;
    constexpr int CIP = ((CIN + 31) / 32) * 32;
    constexpr int NQ = (MODE == 0) ? 1 : 4;
    constexpr int LPW = 36;               // A-tile LDS row stride (ushorts)
    constexpr int NPOUT = (MODE == 0 ? 1 : 4) * M;
    constexpr int NOCP = NOC + 8;         // epilogue LDS row stride

    constexpr int TDY[9] = {1,1,1,0,0,0,0,0,0};
    constexpr int TDX[9] = {1,0,0,1,0,0,1,0,0};
    constexpr int TQ [9] = {3,2,3,1,0,1,3,2,3};

    extern __shared__ ushort sa[];        // max(NPIX*36, NPOUT*NOCP)
    __shared__ float mrall[CIP][2];
    __shared__ float sred[4][16][2];

    const int tid = threadIdx.x;
    const int lane = tid & 63, wv = tid >> 6;
    const int ln = lane & 15, kq = lane >> 4;
    const int wn = wv % NWN, wm = wv / NWN;
    const int grp = tid & 3;              // fixed channel-octet per thread

    int bi = xcd_swz(blockIdx.x, gridDim.x);
    const int xc = bi % XC; bi /= XC;
    const int yc = bi % YC; bi /= YC;
    const int g  = bi % NG;
    const int b  = bi / NG;

    const int ocg = g * NOC + wn * 16 + ln;
    const float b0 = bias[ocg];
    f32x4 acc[NQ][MSUB];
    #pragma unroll
    for (int q = 0; q < NQ; q++)
        #pragma unroll
        for (int s = 0; s < MSUB; s++)
            acc[q][s] = (f32x4){b0, b0, b0, b0};

    for (int e = tid; e < CIP; e += 256) {
        float m = 0.f, r = 0.f;
        if (e < CIN) {
            int c = b * CIN + e;
            float s1 = stats_in[2 * c], s2 = stats_in[2 * c + 1];
            m = s1 * invHWin;
            r = rsqrtf(fmaf(s2, invHWin, -m * m) + EPS_F);
        }
        mrall[e][0] = m; mrall[e][1] = r;
    }

    const ushort* inb = in + (size_t)b * HWIN * CIN;

    for (int c0 = 0; c0 < CIP; c0 += 32) {
        __syncthreads();   // prev tile consumed; mrall visible on iter 0
        const int ch0 = c0 + 8 * grp;
        float m8[8], r8[8];
        #pragma unroll
        for (int j = 0; j < 8; j++) { m8[j] = mrall[ch0 + j][0]; r8[j] = mrall[ch0 + j][1]; }
        for (int pix = tid >> 2; pix < NPIX; pix += 64) {
            int pr = pix / NCO, pc = pix - pr * NCO;
            int gy, gx;
            if (MODE == 0) { gy = 2 * (yc * RT) - 1 + pr; gx = 2 * (xc * CT) - 1 + pc; }
            else           { gy = yc * RT + pr;           gx = xc * CT + pc; }
            ushort8 pk;
            #pragma unroll
            for (int j = 0; j < 8; j++) pk[j] = 0;
            if ((unsigned)gy < (unsigned)WIN && (unsigned)gx < (unsigned)WIN && ch0 < CIN) {
                ushort8 raw = *(const ushort8*)(inb + (size_t)(gy * WIN + gx) * CIN + ch0);
                #pragma unroll
                for (int j = 0; j < 8; j++) {
                    float x = bf2f(raw[j]);
                    pk[j] = f2bf(fmaxf((x - m8[j]) * r8[j], 0.f));
                }
            }
            *(ushort8*)&sa[pix * LPW + grp * 8] = pk;
        }
        __syncthreads();
        #pragma unroll
        for (int t = 0; t < 9; t++) {
            short8 bfr = *(const short8*)&wbf[((size_t)t * COUT + ocg) * CIP + c0 + kq * 8];
            #pragma unroll
            for (int s = 0; s < MSUB; s++) {
                const int mb = wm * MSUB * 16 + s * 16;
                const int r = mb / CT, cb = mb % CT;
                int pix;
                if (MODE == 0) pix = (t / 3 + 2 * r) * NCO + 2 * (cb + ln) + t % 3;
                else           pix = (TDY[t] + r) * NCO + cb + ln + TDX[t];
                short8 afr = *(const short8*)&sa[pix * LPW + kq * 8];
                int qd = (MODE == 0) ? 0 : TQ[t];
                acc[qd][s] = __builtin_amdgcn_mfma_f32_16x16x32_bf16(afr, bfr, acc[qd][s], 0, 0, 0);
            }
        }
    }

    // ---- stats partials (registers only) ----
    float s1 = 0.f, s2 = 0.f;
    #pragma unroll
    for (int q = 0; q < NQ; q++)
        #pragma unroll
        for (int s = 0; s < MSUB; s++)
            #pragma unroll
            for (int rg = 0; rg < 4; rg++) {
                float v = acc[q][s][rg];
                s1 += v; s2 = fmaf(v, v, s2);
            }
    s1 += __shfl_xor(s1, 16); s2 += __shfl_xor(s2, 16);
    s1 += __shfl_xor(s1, 32); s2 += __shfl_xor(s2, 32);
    if (lane < 16) { sred[wv][lane][0] = s1; sred[wv][lane][1] = s2; }

    // ---- assemble outputs in LDS (reuse sa) ----
    __syncthreads();                       // all waves done reading sa
    const int ocl = wn * 16 + ln;
    if (MODE == 0) {
        #pragma unroll
        for (int s = 0; s < MSUB; s++)
            #pragma unroll
            for (int rg = 0; rg < 4; rg++) {
                const int m = wm * MSUB * 16 + s * 16 + kq * 4 + rg;
                sa[m * NOCP + ocl] = f2bf(acc[0][s][rg]);
            }
    } else {
        #pragma unroll
        for (int q = 0; q < 4; q++) {
            const int dy = q >> 1, dx = q & 1;
            #pragma unroll
            for (int s = 0; s < MSUB; s++)
                #pragma unroll
                for (int rg = 0; rg < 4; rg++) {
                    const int m = wm * MSUB * 16 + s * 16 + kq * 4 + rg;
                    const int r = m / CT, c = m % CT;
                    const int lp = (2 * r + dy) * (2 * CT) + 2 * c + dx;
                    sa[lp * NOCP + ocl] = f2bf(acc[q][s][rg]);
                }
        }
    }
    __syncthreads();

    // ---- dense coalesced stores ----
    ushort* ob = out + (size_t)b * HWOUT * COUT + g * NOC;
    for (int e = tid; e < (NPOUT * NOC) / 8; e += 256) {
        int u = e * 8;
        int lp = u / NOC, co = u % NOC;
        int gp;
        if (MODE == 0) {
            int r = lp / CT, c = lp % CT;
            gp = (yc * RT + r) * WOUT + xc * CT + c;
        } else {
            int r2 = lp / (2 * CT), x2 = lp % (2 * CT);
            gp = (2 * (yc * RT) + r2) * WOUT + 2 * (xc * CT) + x2;
        }
        *(ushort8*)&ob[(size_t)gp * COUT + co] = *(const ushort8*)&sa[lp * NOCP + co];
    }

    if (tid < NOC) {
        int wnn = tid >> 4, oc = tid & 15;
        float t1 = 0.f, t2 = 0.f;
        #pragma unroll
        for (int k = 0; k < NMG; k++) {
            t1 += sred[wnn + k * NWN][oc][0];
            t2 += sred[wnn + k * NWN][oc][1];
        }
        int cix = b * COUT + g * NOC + wnn * 16 + oc;
        atomicAdd(&stats_out[2 * cix],     t1);
        atomicAdd(&stats_out[2 * cix + 1], t2);
    }
}

// ---------------------------------------------------------------------------
// L1 dedicated: conv 3x3 s2 p1, 16->32 @512->256. (unchanged from r8)
// ---------------------------------------------------------------------------
__global__ __launch_bounds__(256) void mfconv_l1(
    const ushort* __restrict__ in, const ushort* __restrict__ wbf,
    const float* __restrict__ bias, ushort* __restrict__ out,
    const float* __restrict__ stats_in, float invHWin,
    float* __restrict__ stats_out)
{
    constexpr int WIN = 512, HWIN = WIN * WIN;
    constexpr int WOUT = 256, HWOUT = WOUT * WOUT;
    constexpr int COUT = 32, RT = 4, CT = 32;
    constexpr int NCO = 65, NPIX = 585;     // 9 x 65 halo
    constexpr int NOCP = 40;                // 32 oc + 8 pad

    extern __shared__ ushort sa[];          // max(585*16, 128*40) = 9360 us
    __shared__ float mrall[16][2];
    __shared__ float sred[4][16][2];

    const int tid = threadIdx.x;
    const int lane = tid & 63, wv = tid >> 6;
    const int ln = lane & 15, kq = lane >> 4;
    const int wn = wv & 1, wm = wv >> 1;

    int bi = xcd_swz(blockIdx.x, gridDim.x);
    const int xc = bi & 7;
    const int yc = (bi >> 3) & 63;
    const int b  = bi >> 9;

    const int ocg = wn * 16 + ln;
    const float b0 = bias[ocg];
    f32x4 acc[4];
    #pragma unroll
    for (int s = 0; s < 4; s++) acc[s] = (f32x4){b0, b0, b0, b0};

    if (tid < 16) {
        int c = b * 16 + tid;
        float s1 = stats_in[2 * c], s2 = stats_in[2 * c + 1];
        float m = s1 * invHWin;
        mrall[tid][0] = m;
        mrall[tid][1] = rsqrtf(fmaf(s2, invHWin, -m * m) + EPS_F);
    }

    // Issue all staging loads up front (latency hides under mrall + barrier).
    const int grp = tid & 1, p0 = tid >> 1;
    const ushort* inb = in + (size_t)b * HWIN * 16 + grp * 8;
    ushort8 rw[5];
    bool ok[5];
    #pragma unroll
    for (int i = 0; i < 5; i++) {
        int pix = p0 + i * 128;
        int pr = pix / NCO, pc = pix - pr * NCO;
        int gy = 2 * (yc * RT) - 1 + pr;
        int gx = 2 * (xc * CT) - 1 + pc;
        ok[i] = (pix < NPIX) && ((unsigned)gy < (unsigned)WIN)
                             && ((unsigned)gx < (unsigned)WIN);
        if (ok[i])
            rw[i] = *(const ushort8*)(inb + (size_t)(gy * WIN + gx) * 16);
    }
    __syncthreads();     // mrall ready

    float m8[8], r8[8];
    #pragma unroll
    for (int j = 0; j < 8; j++) {
        m8[j] = mrall[grp * 8 + j][0];
        r8[j] = mrall[grp * 8 + j][1];
    }
    #pragma unroll
    for (int i = 0; i < 5; i++) {
        int pix = p0 + i * 128;
        if (pix < NPIX) {
            ushort8 pk;
            #pragma unroll
            for (int j = 0; j < 8; j++) pk[j] = 0;
            if (ok[i]) {
                #pragma unroll
                for (int j = 0; j < 8; j++) {
                    float x = bf2f(rw[i][j]);
                    pk[j] = f2bf(fmaxf((x - m8[j]) * r8[j], 0.f));
                }
            }
            int ep = (pix * 16 + grp * 8) ^ (((pix >> 2) & 1) << 3);
            *(ushort8*)&sa[ep] = pk;
        }
    }
    __syncthreads();

    // 5 K-chunks; lane's tap = 2c + (kq>>1); ch-octet = kq&1.
    const int tp = kq >> 1, off8 = (kq & 1) * 8;
    #pragma unroll
    for (int c = 0; c < 5; c++) {
        short8 bfr = *(const short8*)&wbf[(size_t)(c * COUT + ocg) * 32 + kq * 8];
        int t = 2 * c + tp; t = t > 8 ? 8 : t;   // c=4,tp=1: weights are 0
        const int ty = t / 3, tx = t - 3 * ty;
        #pragma unroll
        for (int s = 0; s < 4; s++) {
            const int mb = wm * 64 + s * 16;
            const int r = mb >> 5, cb = mb & 31;
            int px = (ty + 2 * r) * NCO + 2 * (cb + ln) + tx;
            int ep = (px * 16 + off8) ^ (((px >> 2) & 1) << 3);
            short8 afr = *(const short8*)&sa[ep];
            acc[s] = __builtin_amdgcn_mfma_f32_16x16x32_bf16(afr, bfr, acc[s], 0, 0, 0);
        }
    }

    // ---- stats partials ----
    float s1 = 0.f, s2 = 0.f;
    #pragma unroll
    for (int s = 0; s < 4; s++)
        #pragma unroll
        for (int rg = 0; rg < 4; rg++) {
            float v = acc[s][rg];
            s1 += v; s2 = fmaf(v, v, s2);
        }
    s1 += __shfl_xor(s1, 16); s2 += __shfl_xor(s2, 16);
    s1 += __shfl_xor(s1, 32); s2 += __shfl_xor(s2, 32);
    if (lane < 16) { sred[wv][lane][0] = s1; sred[wv][lane][1] = s2; }

    // ---- assemble + dense stores ----
    __syncthreads();
    const int ocl = wn * 16 + ln;
    #pragma unroll
    for (int s = 0; s < 4; s++)
        #pragma unroll
        for (int rg = 0; rg < 4; rg++) {
            const int m = wm * 64 + s * 16 + kq * 4 + rg;
            sa[m * NOCP + ocl] = f2bf(acc[s][rg]);
        }
    __syncthreads();
    ushort* ob = out + (size_t)b * HWOUT * COUT;
    for (int e = tid; e < 512; e += 256) {
        int u = e * 8;
        int lp = u >> 5, co = u & 31;
        int r = lp >> 5, c = lp & 31;
        int gp = (yc * RT + r) * WOUT + xc * CT + c;
        *(ushort8*)&ob[(size_t)gp * COUT + co] = *(const ushort8*)&sa[lp * NOCP + co];
    }
    if (tid < 32) {
        int wnn = tid >> 4, oc = tid & 15;
        float t1 = 0.f, t2 = 0.f;
        #pragma unroll
        for (int k = 0; k < 2; k++) {
            t1 += sred[wnn + k * 2][oc][0];
            t2 += sred[wnn + k * 2][oc][1];
        }
        int cix = b * COUT + wnn * 16 + oc;
        atomicAdd(&stats_out[2 * cix],     t1);
        atomicAdd(&stats_out[2 * cix + 1], t2);
    }
}

// ---------------------------------------------------------------------------
// L0: 7x7 reflect conv @512 via MFMA (BFIN=false path only; unchanged r8).
// ---------------------------------------------------------------------------
template<bool BFIN>
__global__ __launch_bounds__(256, 4) void conv7x(
    const float* __restrict__ inf,
    const ushort* __restrict__ wpk, const float* __restrict__ bias,
    ushort* __restrict__ out, float* __restrict__ stats_out)
{
    constexpr int W = 512, HW = 512 * 512;
    constexpr int HCOL = 70;
    constexpr int NPIXH = 980;
    constexpr int SASZ = 12288;

    __shared__ ushort sa[SASZ];
    __shared__ float sred[4][16][2];

    const int tid = threadIdx.x;
    const int lane = tid & 63, wv = tid >> 6;
    const int ln = lane & 15, kq = lane >> 4;

    int bi = xcd_swz(blockIdx.x, gridDim.x);
    const int xc = bi & 7;
    const int yr = (bi >> 3) & 63;
    const int b  = bi >> 9;
    const int y0 = yr * 8, x0 = xc * 64;

    {
        const float* p0 = inf + (size_t)b * 3 * HW;
        for (int pix = tid; pix < NPIXH; pix += 256) {
            int pr = pix / HCOL, pc = pix - pr * HCOL;
            int gy = reflect512(y0 - 3 + pr);
            int gx = reflect512(x0 - 3 + pc);
            const float* p = p0 + gy * W + gx;
            ushort4v pk;
            pk[0] = f2bf(p[0]); pk[1] = f2bf(p[HW]);
            pk[2] = f2bf(p[2 * (size_t)HW]); pk[3] = 0;
            *(ushort4v*)&sa[pix * 4] = pk;
        }
        if (tid < 16) sa[980 * 4 + tid] = 0;    // zero pad (dx=7 tail reads)
    }
    __syncthreads();

    const float b0 = bias[ln];
    f32x4 acc[8];
    #pragma unroll
    for (int s = 0; s < 8; s++) acc[s] = (f32x4){b0, b0, b0, b0};

    {
        // Wave owns rows 0..7, cols c0..c0+15. A-frag = 2 adjacent px x 4ch.
        const int c0 = wv * 16;
        const int abase = (c0 + ln + 2 * kq) * 4;
        const ushort* wp0 = wpk + ((size_t)kq * 16 + ln) * 8;
        short8 bw[7];
        #pragma unroll
        for (int ty = 0; ty < 7; ty++)
            bw[ty] = *(const short8*)(wp0 + (size_t)ty * 512);
        #pragma unroll
        for (int R = 0; R < 14; R++) {
            short8 afr = *(const short8*)&sa[abase + R * (HCOL * 4)];
            #pragma unroll
            for (int ty = 0; ty < 7; ty++) {
                const int s = R - ty;
                if (s >= 0 && s < 8)
                    acc[s] = __builtin_amdgcn_mfma_f32_16x16x32_bf16(afr, bw[ty], acc[s], 0, 0, 0);
            }
        }
    }

    // stats partials first (registers), then LDS-assembled NHWC store.
    float s1 = 0.f, s2 = 0.f;
    #pragma unroll
    for (int s = 0; s < 8; s++)
        #pragma unroll
        for (int rg = 0; rg < 4; rg++) {
            float v = acc[s][rg];
            s1 += v; s2 = fmaf(v, v, s2);
        }
    s1 += __shfl_xor(s1, 16); s2 += __shfl_xor(s2, 16);
    s1 += __shfl_xor(s1, 32); s2 += __shfl_xor(s2, 32);
    if (lane < 16) { sred[wv][lane][0] = s1; sred[wv][lane][1] = s2; }

    __syncthreads();   // A-tile reads done; reuse sa as [512][24]
    #pragma unroll
    for (int s = 0; s < 8; s++)
        #pragma unroll
        for (int rg = 0; rg < 4; rg++) {
            int m = s * 64 + wv * 16 + kq * 4 + rg;
            sa[m * 24 + ln] = f2bf(acc[s][rg]);
        }
    __syncthreads();
    ushort* ob = out + (size_t)b * HW * 16;
    for (int e = tid; e < 1024; e += 256) {
        int u = e * 8;
        int lp = u >> 4, co = u & 15;
        int gp = (y0 + (lp >> 6)) * W + x0 + (lp & 63);
        *(ushort8*)&ob[(size_t)gp * 16 + co] = *(const ushort8*)&sa[lp * 24 + co];
    }
    if (tid < 16) {
        float t1 = 0.f, t2 = 0.f;
        #pragma unroll
        for (int k = 0; k < 4; k++) { t1 += sred[k][tid][0]; t2 += sred[k][tid][1]; }
        int cix = b * 16 + tid;
        atomicAdd(&stats_out[2 * cix],     t1);
        atomicAdd(&stats_out[2 * cix + 1], t2);
    }
}

// ---------------------------------------------------------------------------
// L9 PERSISTENT: 7x7 16->3 @512 + norm + tanh + seg. 1024 blocks x 4 tiles.
// Double-buffered A-tile; per iter: issue loads(t+1) -> MFMA(t) [disjoint
// buffers, no barrier between] -> vmcnt+norm+write(t+1) -> sf epilogue
// (its 2 barriers double as the swap fences). Load latency hides under MFMA.
// r9 FIX: NO min-occupancy clamp. r8's __launch_bounds__(256,4) forced the
// allocator to 64 VGPR; the pipeline working set (rw 20 + bw 28 + acc 16 +
// addr) needs ~100 -> rw spilled to scratch = 180 MB scratch round-trips,
// 126 us. LDS (40 KB -> 4 blocks/CU) bounds residency anyway.
// ---------------------------------------------------------------------------
__global__ __launch_bounds__(256) void conv7x_l9p(
    const ushort* __restrict__ inb16, const ushort* __restrict__ wpk,
    const float* __restrict__ bias, const float* __restrict__ stats_in,
    float invHWin, const int* __restrict__ inst, float* __restrict__ segacc)
{
    constexpr int W = 512, HW = 512 * 512;
    constexpr int HCOL = 38, STR = 16;
    constexpr int SA1 = 8544;              // 532*16 + 32 pad

    __shared__ ushort sa[2][SA1];
    __shared__ float sf[1280];
    __shared__ float mr[16][2];
    __shared__ float segl[128];

    const int tid = threadIdx.x;
    const int lane = tid & 63, wv = tid >> 6;
    const int ln = lane & 15, kq = lane >> 4;

    const int L  = (blockIdx.x & 7) * 128 + (blockIdx.x >> 3);
    const int t0 = L * 4;
    const int b  = t0 >> 10;
    const int yr = (t0 >> 4) & 63;
    const int xcb = t0 & 15;
    const int y0 = yr * 8;

    const int h = tid & 1;
    const ushort* inbb = inb16 + (size_t)b * HW * 16 + 8 * h;
    const int* ib = inst + ((size_t)b << 18);

    ushort8 rw[5];

#define L9_ISSUE(X0) do {                                                   \
    _Pragma("unroll")                                                       \
    for (int i2 = 0; i2 < 5; i2++) {                                        \
        int pix = (tid >> 1) + i2 * 128;                                    \
        if (pix < 532) {                                                    \
            int pr = pix / HCOL, pc = pix - pr * HCOL;                      \
            int gy = reflect512(y0 - 3 + pr);                               \
            int gx = reflect512((X0) - 3 + pc);                             \
            rw[i2] = *(const ushort8*)(inbb + (size_t)(gy * W + gx) * 16);  \
        } } } while (0)

#define L9_WRITE(BUF) do {                                                  \
    _Pragma("unroll")                                                       \
    for (int i2 = 0; i2 < 5; i2++) {                                        \
        int pix = (tid >> 1) + i2 * 128;                                    \
        if (pix < 532) {                                                    \
            union { ushort8 us; unsigned u[4]; } P;                         \
            _Pragma("unroll")                                               \
            for (int q2 = 0; q2 < 4; q2++) {                                \
                float lo = fmaxf(fmaf(bf2f(rw[i2][2*q2]),   r8[2*q2],   nm8[2*q2]),   0.f); \
                float hi = fmaxf(fmaf(bf2f(rw[i2][2*q2+1]), r8[2*q2+1], nm8[2*q2+1]), 0.f); \
                P.u[q2] = cvt_pk_bf16(lo, hi);                              \
            }                                                               \
            *(ushort8*)&sa[BUF][pix * STR + 8 * h] = P.us;                  \
        } } } while (0)

    // ---- prologue: stage tile 0 ----
    L9_ISSUE(xcb * 32);
    if (tid < 16) {
        int c = b * 16 + tid;
        float s1 = stats_in[2 * c], s2 = stats_in[2 * c + 1];
        float m = s1 * invHWin;
        mr[tid][0] = m;
        mr[tid][1] = rsqrtf(fmaf(s2, invHWin, -m * m) + EPS_F);
    }
    if (tid < 128) segl[tid] = 0.f;
    if (tid >= 128 && tid < 160) {           // zero pads of both buffers
        sa[0][8512 + (tid - 128)] = 0;
        sa[1][8512 + (tid - 128)] = 0;
    }
    __syncthreads();                         // mr + pads ready

    float r8[8], nm8[8];
    #pragma unroll
    for (int j = 0; j < 8; j++) {
        r8[j]  = mr[8 * h + j][1];
        nm8[j] = -mr[8 * h + j][0] * r8[j];
    }
    L9_WRITE(0);
    int lab_next = ib[(y0 + (tid >> 5)) * W + xcb * 32 + (tid & 31)] & 31;
    __syncthreads();                         // buf0 ready

    const int wr = wv >> 1, wc = wv & 1;
    const int abase = ((wr * 4) * HCOL + wc * 16 + ln + (kq >> 1)) * STR + (kq & 1) * 8;
    const ushort* wp9 = wpk + ((size_t)kq * 16 + ln) * 8;
    const float b0 = (ln < 3) ? bias[ln] : 0.f;

    for (int it = 0; it < 4; ++it) {
        const int cur = it & 1;
        const int mylab = lab_next;
        // a: issue next tile's loads (consumed after MFMA -> latency hidden)
        if (it < 3) {
            L9_ISSUE((xcb + it + 1) * 32);
            lab_next = ib[(y0 + (tid >> 5)) * W + (xcb + it + 1) * 32 + (tid & 31)] & 31;
        }
        // b: MFMA from sa[cur]
        f32x4 acc[4];
        #pragma unroll
        for (int s = 0; s < 4; s++) acc[s] = (f32x4){b0, b0, b0, b0};
        #pragma unroll
        for (int q = 0; q < 4; q++) {
            short8 bw[7];
            #pragma unroll
            for (int ty = 0; ty < 7; ty++)
                bw[ty] = *(const short8*)(wp9 + (size_t)(ty * 4 + q) * 512);
            #pragma unroll
            for (int rr = 0; rr < 10; rr++) {
                short8 afr = *(const short8*)&sa[cur][abase + q * (2 * STR) + rr * (HCOL * STR)];
                #pragma unroll
                for (int ty = 0; ty < 7; ty++) {
                    const int s = rr - ty;
                    if (s >= 0 && s < 4)
                        acc[s] = __builtin_amdgcn_mfma_f32_16x16x32_bf16(afr, bw[ty], acc[s], 0, 0, 0);
                }
            }
        }
        // d: write next tile into the OTHER buffer (disjoint; no barrier yet)
        if (it < 3) L9_WRITE(cur ^ 1);
        // e: sf epilogue (barriers double as swap fences)
        if (ln < 3) {
            #pragma unroll
            for (int s = 0; s < 4; s++)
                #pragma unroll
                for (int rg = 0; rg < 4; rg++) {
                    int m = (wr * 4 + s) * 32 + wc * 16 + kq * 4 + rg;
                    sf[m * 5 + ln] = acc[s][rg];
                }
        }
        __syncthreads();
        atomicAdd(&segl[mylab * 4 + 0], fast_tanh(sf[tid * 5 + 0]));
        atomicAdd(&segl[mylab * 4 + 1], fast_tanh(sf[tid * 5 + 1]));
        atomicAdd(&segl[mylab * 4 + 2], fast_tanh(sf[tid * 5 + 2]));
        atomicAdd(&segl[mylab * 4 + 3], 1.f);
        __syncthreads();                     // sf reuse + buffer swap fence
    }

    if (tid < 128) {
        float v = segl[tid];
        if (v != 0.f)
            atomicAdd(&segacc[(blockIdx.x & 7) * 128 + tid], v);  // 8 shards
    }
#undef L9_ISSUE
#undef L9_WRITE
}

// ---------------------------------------------------------------------------
// Segment finalize (reduce 8 shards) + scatter (vectorized: 4 px/thread).
// ---------------------------------------------------------------------------
#define HW9 262144
__global__ void seg_final(const float* __restrict__ acc, float* __restrict__ means)
{
    int i = threadIdx.x;
    if (i < 96) {
        int s = i / 3, c = i - s * 3;
        float num = 0.f, den = 0.f;
        #pragma unroll
        for (int k = 0; k < 8; k++) {
            num += acc[k * 128 + s * 4 + c];
            den += acc[k * 128 + s * 4 + 3];
        }
        means[i] = num / fmaxf(den, 1.f);
    }
}

__global__ __launch_bounds__(256) void seg_scatter(
    const int* __restrict__ inst, const float* __restrict__ means,
    float* __restrict__ out)
{
    int p4 = blockIdx.x * 256 + threadIdx.x;   // 4-pixel unit
    int b  = p4 >> 16;                          // 65536 units per batch
    int r4 = (p4 & 65535) * 4;
    const int4v labs = *(const int4v*)(inst + ((size_t)b << 18) + r4);
    float* ob = out + (size_t)b * 3 * HW9 + r4;
    f32x4 o0, o1, o2;
    #pragma unroll
    for (int j = 0; j < 4; j++) {
        int l3 = (labs[j] & 31) * 3;
        o0[j] = means[l3]; o1[j] = means[l3 + 1]; o2[j] = means[l3 + 2];
    }
    *(f32x4*)(ob)           = o0;
    *(f32x4*)(ob + HW9)     = o1;
    *(f32x4*)(ob + 2 * HW9) = o2;
}

// ---------------------------------------------------------------------------
// Launch.
// ---------------------------------------------------------------------------
extern "C" void kernel_launch(void* const* d_in, const int* in_sizes, int n_in,
                              void* d_out, int out_size, void* d_ws, size_t ws_size,
                              hipStream_t stream)
{
    const float* x_in = (const float*)d_in[0];
    const int*   inst = (const int*)d_in[1];
    const float* W_[10];
    const float* Bs[10];
    for (int i = 0; i < 10; i++) {
        W_[i] = (const float*)d_in[2 + 2 * i];
        Bs[i] = (const float*)d_in[3 + 2 * i];
    }
    float* out = (float*)d_out;

    // NHWC bf16 activation ping-pong + fp32 stats + bf16 weights.
    ushort* Ab  = (ushort*)d_ws;            // 16,777,216 el
    ushort* Bb2 = Ab + (size_t)16777216;    //  8,388,608 el
    float*  st  = (float*)(Bb2 + (size_t)8388608);
    const int coff[9] = {0, 128, 384, 896, 1920, 3968, 4992, 5504, 5760};
    float* s_[9];
    for (int i = 0; i < 9; i++) s_[i] = st + coff[i];
    float* segacc = st + 5888;              // 8 shards x 128 = 1024 floats
    float* means  = st + 6912;              // 96 floats
    ushort* wb = (ushort*)(st + 8192);
    const size_t OW1 = 0, OW2 = 9216, OW3 = 27648, OW4 = 101376,
                 OW5 = 396288, OW6 = 691200, OW7 = 764928, OW8 = 783360;
    ushort* wb0 = wb + 790000;
    ushort* wb9 = wb0 + 6656;   // L9 pack: 28 chunks x 512 = 14336 ushorts

    hipMemsetAsync(st, 0, 6912 * sizeof(float), stream);

    WprepArgs wa;
    for (int i = 0; i < 10; i++) wa.w[i] = W_[i];
    wa.d[0] = wb0;
    wa.d[1] = wb + OW1; wa.d[2] = wb + OW2; wa.d[3] = wb + OW3; wa.d[4] = wb + OW4;
    wa.d[5] = wb + OW5; wa.d[6] = wb + OW6; wa.d[7] = wb + OW7; wa.d[8] = wb + OW8;
    wa.d[9] = wb9;
    wprep_all<<<dim3(3132), dim3(256), 0, stream>>>(wa);

    // L0: 7x7 3->16 @512, fp32 NCHW in -> NHWC bf16 out + stats. grid 2048.
    conv7x<false><<<dim3(2048), dim3(256), 0, stream>>>(
        x_in, wb0, Bs[0], Ab, s_[0]);

    // L1: conv 16->32 @512->256 (dedicated kernel, stride-16 A-tile). grid 2048.
    mfconv_l1<<<dim3(2048), dim3(256), 18720, stream>>>(
        Ab, wb + OW1, Bs[1], Bb2, s_[0], 1.f / 262144.f, s_[1]);

    // L2: conv 32->64 @256->128. grid 1024.
    mfconv<32, 64, 256, 0, 2, 4, 4, 32><<<dim3(1024), dim3(256), 42120, stream>>>(
        Bb2, wb + OW2, Bs[2], Ab, s_[1], 1.f / 65536.f, s_[2]);

    // L3: conv 64->128 @128->64. grid 512.
    mfconv<64, 128, 128, 0, 2, 4, 4, 32><<<dim3(512), dim3(256), 42120, stream>>>(
        Ab, wb + OW3, Bs[3], Bb2, s_[2], 1.f / 16384.f, s_[3]);

    // L4: conv 128->256 @64->32. grid 512.
    mfconv<128, 256, 64, 0, 2, 2, 2, 32><<<dim3(512), dim3(256), 23400, stream>>>(
        Bb2, wb + OW4, Bs[4], Ab, s_[3], 1.f / 4096.f, s_[4]);

    // L5: deconv 256->128 @32->64. grid 512. LDS 12288 (epilogue-sized).
    mfconv<256, 128, 32, 1, 1, 1, 2, 32><<<dim3(512), dim3(256), 12288, stream>>>(
        Ab, wb + OW5, Bs[5], Bb2, s_[4], 1.f / 1024.f, s_[5]);

    // L6: deconv 128->64 @64->128. grid 512. LDS 20480.
    mfconv<128, 64, 64, 1, 2, 2, 2, 32><<<dim3(512), dim3(256), 20480, stream>>>(
        Bb2, wb + OW6, Bs[6], Ab, s_[5], 1.f / 4096.f, s_[6]);

    // L7: deconv 64->32 @128->256. grid 1024. LDS 20480.
    mfconv<64, 32, 128, 1, 2, 2, 2, 32><<<dim3(1024), dim3(256), 20480, stream>>>(
        Ab, wb + OW7, Bs[7], Bb2, s_[6], 1.f / 16384.f, s_[7]);

    // L8: deconv 32->16 @256->512. M=128, grid 2048. LDS 24576.
    mfconv<32, 16, 256, 1, 1, 2, 2, 64><<<dim3(2048), dim3(256), 24576, stream>>>(
        Bb2, wb + OW8, Bs[8], Ab, s_[7], 1.f / 65536.f, s_[8]);

    // L9: persistent double-buffered. 1024 blocks x 4 tiles (8x32 each).
    conv7x_l9p<<<dim3(1024), dim3(256), 0, stream>>>(
        Ab, wb9, Bs[9], s_[8], 1.f / 262144.f, inst, segacc);

    seg_final<<<dim3(1), dim3(96), 0, stream>>>(segacc, means);
    seg_scatter<<<dim3(1024), dim3(256), 0, stream>>>(inst, means, out);
}

// Round 11
// 412.427 us; speedup vs baseline: 1.1871x; 1.0923x over previous
//
#include <hip/hip_runtime.h>
#include <math.h>

#define EPS_F 1e-5f

typedef __attribute__((ext_vector_type(8))) short short8;
typedef __attribute__((ext_vector_type(4))) float f32x4;
typedef __attribute__((ext_vector_type(8))) unsigned short ushort8;
typedef __attribute__((ext_vector_type(4))) unsigned short ushort4v;
typedef __attribute__((ext_vector_type(4))) int int4v;

__device__ __forceinline__ int reflect512(int v) {
    v = v < 0 ? -v : v;
    return v >= 512 ? 1022 - v : v;
}

// XCD-aware block swizzle: consecutive LOGICAL tiles share input rows; map
// them to the same XCD (HW round-robins launched id % 8) so halo/row
// re-reads hit the XCD-local L2 instead of L3. Bijective when n % 8 == 0.
__device__ __forceinline__ int xcd_swz(int L, int n) {
    return (L & 7) * (n >> 3) + (L >> 3);
}

// float -> bf16 bits, round-to-nearest-even
__device__ __forceinline__ ushort f2bf(float f) {
    union { float f; unsigned u; } v; v.f = f;
    unsigned r = v.u + 0x7FFFu + ((v.u >> 16) & 1u);
    return (ushort)(r >> 16);
}
__device__ __forceinline__ float bf2f(ushort u) {
    union { unsigned u; float f; } v; v.u = (unsigned)u << 16;
    return v.f;
}

// 2x f32 -> packed bf16 (RNE) in ONE instruction (no builtin on gfx950).
__device__ __forceinline__ unsigned cvt_pk_bf16(float lo, float hi) {
    unsigned r;
    asm("v_cvt_pk_bf16_f32 %0, %1, %2" : "=v"(r) : "v"(lo), "v"(hi));
    return r;
}

// tanh via hardware exp2 + rcp: ~7 VALU ops vs libm's ~25+.
__device__ __forceinline__ float fast_tanh(float x) {
    float cx = fminf(fmaxf(x, -9.f), 9.f);
    float e  = __builtin_amdgcn_exp2f(cx * 2.8853900817779268f); // 2*log2(e)
    return (e - 1.f) * __builtin_amdgcn_rcpf(e + 1.f);
}

// ---------------------------------------------------------------------------
// Weight prep, single fused dispatch. (unchanged)
// ---------------------------------------------------------------------------
template<int CIN, int COUT, bool DEC>
__device__ __forceinline__ void wp_mid(
    const float* __restrict__ w, ushort* __restrict__ dst, int i)
{
    constexpr int CIP = ((CIN + 31) / 32) * 32;
    int ci = i % CIP;
    int oc = (i / CIP) % COUT;
    int t  = i / (CIP * COUT);
    float x = 0.f;
    if (ci < CIN)
        x = DEC ? w[((size_t)ci * COUT + oc) * 9 + t]
                : w[((size_t)oc * CIN + ci) * 9 + t];
    dst[i] = f2bf(x);
}

// L1 conv 16->32: chunk c covers taps (2c, 2c+1); chunk 4 pads tap 9 with 0.
__device__ __forceinline__ void wp_l1(
    const float* __restrict__ w, ushort* __restrict__ dst, int i)
{
    int k  = i & 31;
    int oc = (i >> 5) & 31;
    int c  = i >> 10;
    int tapsel = k >> 4, ci = k & 15;
    int t = 2 * c + tapsel;
    float x = (t < 9) ? w[((size_t)oc * 16 + ci) * 9 + t] : 0.f;
    dst[i] = f2bf(x);
}

template<bool L9>
__device__ __forceinline__ void wp_7(
    const float* __restrict__ w, ushort* __restrict__ dst, int i)
{
    int j   = i & 7;
    int oc  = (i >> 3) & 15;
    int kqe = (i >> 7) & 3;
    int cn  = i >> 9;
    float x = 0.f;
    if (L9) {
        // chunk cn = ty*4 + q; k = kqe*8+j; tapsel=k>>4; ci=k&15; tx=2q+tapsel.
        int k = kqe * 8 + j;
        int tapsel = k >> 4, ci = k & 15;
        int ty = cn >> 2, q = cn & 3;
        int tx = 2 * q + tapsel;
        if (tx < 7 && oc < 3 && ty < 7)
            x = w[((size_t)oc * 16 + ci) * 49 + ty * 7 + tx];
    } else {
        // chunk cn = ty (0..6); k = kqe*8+j; dx=k>>2; ci=k&3.
        int k = kqe * 8 + j;
        int dx = k >> 2, ci = k & 3;
        if (dx < 7 && ci < 3)
            x = w[((size_t)oc * 3 + ci) * 49 + cn * 7 + dx];
    }
    dst[i] = f2bf(x);
}

struct WprepArgs {
    const float* w[10];
    ushort* d[10];   // d[0]=L0 pack, d[1..8]=mid (d[1]=L1 pack), d[9]=L9 pack
};

__global__ __launch_bounds__(256) void wprep_all(WprepArgs a)
{
    int bi = blockIdx.x;
    int t  = threadIdx.x;
    if      (bi < 20)   wp_l1(a.w[1], a.d[1], (bi        ) * 256 + t);
    else if (bi < 92)   wp_mid<32,  64,  false>(a.w[2], a.d[2], (bi - 20   ) * 256 + t);
    else if (bi < 380)  wp_mid<64,  128, false>(a.w[3], a.d[3], (bi - 92   ) * 256 + t);
    else if (bi < 1532) wp_mid<128, 256, false>(a.w[4], a.d[4], (bi - 380  ) * 256 + t);
    else if (bi < 2684) wp_mid<256, 128, true >(a.w[5], a.d[5], (bi - 1532 ) * 256 + t);
    else if (bi < 2972) wp_mid<128, 64,  true >(a.w[6], a.d[6], (bi - 2684 ) * 256 + t);
    else if (bi < 3044) wp_mid<64,  32,  true >(a.w[7], a.d[7], (bi - 2972 ) * 256 + t);
    else if (bi < 3062) wp_mid<32,  16,  true >(a.w[8], a.d[8], (bi - 3044 ) * 256 + t);
    else if (bi < 3076) wp_7<false>(a.w[0], a.d[0], (bi - 3062) * 256 + t);
    else                wp_7<true >(a.w[9], a.d[9], (bi - 3076) * 256 + t);
}

// ---------------------------------------------------------------------------
// MFMA implicit-GEMM conv (MODE 0: 3x3 s2 p1) / deconv (MODE 1: k3 s2 p1 op1).
// (unchanged; used for L2..L8)
// ---------------------------------------------------------------------------
template<int CIN, int COUT, int WIN, int MODE, int NWN, int MSUB, int RT, int CT>
__global__ __launch_bounds__(256) void mfconv(
    const ushort* __restrict__ in, const ushort* __restrict__ wbf,
    const float* __restrict__ bias, ushort* __restrict__ out,
    const float* __restrict__ stats_in, float invHWin,
    float* __restrict__ stats_out)
{
    constexpr int HWIN = WIN * WIN;
    constexpr int WOUT = (MODE == 0) ? (WIN / 2) : (WIN * 2);
    constexpr int HWOUT = WOUT * WOUT;
    constexpr int NMG = 4 / NWN;
    constexpr int NOC = NWN * 16;
    constexpr int M = NMG * MSUB * 16;
    static_assert(M == RT * CT, "tile mismatch");
    constexpr int SPAN = (MODE == 0) ? WOUT : WIN;
    constexpr int XC = SPAN / CT, YC = SPAN / RT;
    constexpr int NG = COUT / NOC;
    constexpr int NR = (MODE == 0) ? (2 * RT + 1) : (RT + 1);
    constexpr int NCO = (MODE == 0) ? (2 * CT + 1) : (CT + 1);
    constexpr int NPIX = NR * NCO;
    constexpr int CIP = ((CIN + 31) / 32) * 32;
    constexpr int NQ = (MODE == 0) ? 1 : 4;
    constexpr int LPW = 36;               // A-tile LDS row stride (ushorts)
    constexpr int NPOUT = (MODE == 0 ? 1 : 4) * M;
    constexpr int NOCP = NOC + 8;         // epilogue LDS row stride

    constexpr int TDY[9] = {1,1,1,0,0,0,0,0,0};
    constexpr int TDX[9] = {1,0,0,1,0,0,1,0,0};
    constexpr int TQ [9] = {3,2,3,1,0,1,3,2,3};

    extern __shared__ ushort sa[];        // max(NPIX*36, NPOUT*NOCP)
    __shared__ float mrall[CIP][2];
    __shared__ float sred[4][16][2];

    const int tid = threadIdx.x;
    const int lane = tid & 63, wv = tid >> 6;
    const int ln = lane & 15, kq = lane >> 4;
    const int wn = wv % NWN, wm = wv / NWN;
    const int grp = tid & 3;              // fixed channel-octet per thread

    int bi = xcd_swz(blockIdx.x, gridDim.x);
    const int xc = bi % XC; bi /= XC;
    const int yc = bi % YC; bi /= YC;
    const int g  = bi % NG;
    const int b  = bi / NG;

    const int ocg = g * NOC + wn * 16 + ln;
    const float b0 = bias[ocg];
    f32x4 acc[NQ][MSUB];
    #pragma unroll
    for (int q = 0; q < NQ; q++)
        #pragma unroll
        for (int s = 0; s < MSUB; s++)
            acc[q][s] = (f32x4){b0, b0, b0, b0};

    for (int e = tid; e < CIP; e += 256) {
        float m = 0.f, r = 0.f;
        if (e < CIN) {
            int c = b * CIN + e;
            float s1 = stats_in[2 * c], s2 = stats_in[2 * c + 1];
            m = s1 * invHWin;
            r = rsqrtf(fmaf(s2, invHWin, -m * m) + EPS_F);
        }
        mrall[e][0] = m; mrall[e][1] = r;
    }

    const ushort* inb = in + (size_t)b * HWIN * CIN;

    for (int c0 = 0; c0 < CIP; c0 += 32) {
        __syncthreads();   // prev tile consumed; mrall visible on iter 0
        const int ch0 = c0 + 8 * grp;
        float m8[8], r8[8];
        #pragma unroll
        for (int j = 0; j < 8; j++) { m8[j] = mrall[ch0 + j][0]; r8[j] = mrall[ch0 + j][1]; }
        for (int pix = tid >> 2; pix < NPIX; pix += 64) {
            int pr = pix / NCO, pc = pix - pr * NCO;
            int gy, gx;
            if (MODE == 0) { gy = 2 * (yc * RT) - 1 + pr; gx = 2 * (xc * CT) - 1 + pc; }
            else           { gy = yc * RT + pr;           gx = xc * CT + pc; }
            ushort8 pk;
            #pragma unroll
            for (int j = 0; j < 8; j++) pk[j] = 0;
            if ((unsigned)gy < (unsigned)WIN && (unsigned)gx < (unsigned)WIN && ch0 < CIN) {
                ushort8 raw = *(const ushort8*)(inb + (size_t)(gy * WIN + gx) * CIN + ch0);
                #pragma unroll
                for (int j = 0; j < 8; j++) {
                    float x = bf2f(raw[j]);
                    pk[j] = f2bf(fmaxf((x - m8[j]) * r8[j], 0.f));
                }
            }
            *(ushort8*)&sa[pix * LPW + grp * 8] = pk;
        }
        __syncthreads();
        #pragma unroll
        for (int t = 0; t < 9; t++) {
            short8 bfr = *(const short8*)&wbf[((size_t)t * COUT + ocg) * CIP + c0 + kq * 8];
            #pragma unroll
            for (int s = 0; s < MSUB; s++) {
                const int mb = wm * MSUB * 16 + s * 16;
                const int r = mb / CT, cb = mb % CT;
                int pix;
                if (MODE == 0) pix = (t / 3 + 2 * r) * NCO + 2 * (cb + ln) + t % 3;
                else           pix = (TDY[t] + r) * NCO + cb + ln + TDX[t];
                short8 afr = *(const short8*)&sa[pix * LPW + kq * 8];
                int qd = (MODE == 0) ? 0 : TQ[t];
                acc[qd][s] = __builtin_amdgcn_mfma_f32_16x16x32_bf16(afr, bfr, acc[qd][s], 0, 0, 0);
            }
        }
    }

    // ---- stats partials (registers only) ----
    float s1 = 0.f, s2 = 0.f;
    #pragma unroll
    for (int q = 0; q < NQ; q++)
        #pragma unroll
        for (int s = 0; s < MSUB; s++)
            #pragma unroll
            for (int rg = 0; rg < 4; rg++) {
                float v = acc[q][s][rg];
                s1 += v; s2 = fmaf(v, v, s2);
            }
    s1 += __shfl_xor(s1, 16); s2 += __shfl_xor(s2, 16);
    s1 += __shfl_xor(s1, 32); s2 += __shfl_xor(s2, 32);
    if (lane < 16) { sred[wv][lane][0] = s1; sred[wv][lane][1] = s2; }

    // ---- assemble outputs in LDS (reuse sa) ----
    __syncthreads();                       // all waves done reading sa
    const int ocl = wn * 16 + ln;
    if (MODE == 0) {
        #pragma unroll
        for (int s = 0; s < MSUB; s++)
            #pragma unroll
            for (int rg = 0; rg < 4; rg++) {
                const int m = wm * MSUB * 16 + s * 16 + kq * 4 + rg;
                sa[m * NOCP + ocl] = f2bf(acc[0][s][rg]);
            }
    } else {
        #pragma unroll
        for (int q = 0; q < 4; q++) {
            const int dy = q >> 1, dx = q & 1;
            #pragma unroll
            for (int s = 0; s < MSUB; s++)
                #pragma unroll
                for (int rg = 0; rg < 4; rg++) {
                    const int m = wm * MSUB * 16 + s * 16 + kq * 4 + rg;
                    const int r = m / CT, c = m % CT;
                    const int lp = (2 * r + dy) * (2 * CT) + 2 * c + dx;
                    sa[lp * NOCP + ocl] = f2bf(acc[q][s][rg]);
                }
        }
    }
    __syncthreads();

    // ---- dense coalesced stores ----
    ushort* ob = out + (size_t)b * HWOUT * COUT + g * NOC;
    for (int e = tid; e < (NPOUT * NOC) / 8; e += 256) {
        int u = e * 8;
        int lp = u / NOC, co = u % NOC;
        int gp;
        if (MODE == 0) {
            int r = lp / CT, c = lp % CT;
            gp = (yc * RT + r) * WOUT + xc * CT + c;
        } else {
            int r2 = lp / (2 * CT), x2 = lp % (2 * CT);
            gp = (2 * (yc * RT) + r2) * WOUT + 2 * (xc * CT) + x2;
        }
        *(ushort8*)&ob[(size_t)gp * COUT + co] = *(const ushort8*)&sa[lp * NOCP + co];
    }

    if (tid < NOC) {
        int wnn = tid >> 4, oc = tid & 15;
        float t1 = 0.f, t2 = 0.f;
        #pragma unroll
        for (int k = 0; k < NMG; k++) {
            t1 += sred[wnn + k * NWN][oc][0];
            t2 += sred[wnn + k * NWN][oc][1];
        }
        int cix = b * COUT + g * NOC + wnn * 16 + oc;
        atomicAdd(&stats_out[2 * cix],     t1);
        atomicAdd(&stats_out[2 * cix + 1], t2);
    }
}

// ---------------------------------------------------------------------------
// L1 dedicated: conv 3x3 s2 p1, 16->32 @512->256. (unchanged)
// ---------------------------------------------------------------------------
__global__ __launch_bounds__(256) void mfconv_l1(
    const ushort* __restrict__ in, const ushort* __restrict__ wbf,
    const float* __restrict__ bias, ushort* __restrict__ out,
    const float* __restrict__ stats_in, float invHWin,
    float* __restrict__ stats_out)
{
    constexpr int WIN = 512, HWIN = WIN * WIN;
    constexpr int WOUT = 256, HWOUT = WOUT * WOUT;
    constexpr int COUT = 32, RT = 4, CT = 32;
    constexpr int NCO = 65, NPIX = 585;     // 9 x 65 halo
    constexpr int NOCP = 40;                // 32 oc + 8 pad

    extern __shared__ ushort sa[];          // max(585*16, 128*40) = 9360 us
    __shared__ float mrall[16][2];
    __shared__ float sred[4][16][2];

    const int tid = threadIdx.x;
    const int lane = tid & 63, wv = tid >> 6;
    const int ln = lane & 15, kq = lane >> 4;
    const int wn = wv & 1, wm = wv >> 1;

    int bi = xcd_swz(blockIdx.x, gridDim.x);
    const int xc = bi & 7;
    const int yc = (bi >> 3) & 63;
    const int b  = bi >> 9;

    const int ocg = wn * 16 + ln;
    const float b0 = bias[ocg];
    f32x4 acc[4];
    #pragma unroll
    for (int s = 0; s < 4; s++) acc[s] = (f32x4){b0, b0, b0, b0};

    if (tid < 16) {
        int c = b * 16 + tid;
        float s1 = stats_in[2 * c], s2 = stats_in[2 * c + 1];
        float m = s1 * invHWin;
        mrall[tid][0] = m;
        mrall[tid][1] = rsqrtf(fmaf(s2, invHWin, -m * m) + EPS_F);
    }

    // Issue all staging loads up front (latency hides under mrall + barrier).
    const int grp = tid & 1, p0 = tid >> 1;
    const ushort* inb = in + (size_t)b * HWIN * 16 + grp * 8;
    ushort8 rw[5];
    bool ok[5];
    #pragma unroll
    for (int i = 0; i < 5; i++) {
        int pix = p0 + i * 128;
        int pr = pix / NCO, pc = pix - pr * NCO;
        int gy = 2 * (yc * RT) - 1 + pr;
        int gx = 2 * (xc * CT) - 1 + pc;
        ok[i] = (pix < NPIX) && ((unsigned)gy < (unsigned)WIN)
                             && ((unsigned)gx < (unsigned)WIN);
        if (ok[i])
            rw[i] = *(const ushort8*)(inb + (size_t)(gy * WIN + gx) * 16);
    }
    __syncthreads();     // mrall ready

    float m8[8], r8[8];
    #pragma unroll
    for (int j = 0; j < 8; j++) {
        m8[j] = mrall[grp * 8 + j][0];
        r8[j] = mrall[grp * 8 + j][1];
    }
    #pragma unroll
    for (int i = 0; i < 5; i++) {
        int pix = p0 + i * 128;
        if (pix < NPIX) {
            ushort8 pk;
            #pragma unroll
            for (int j = 0; j < 8; j++) pk[j] = 0;
            if (ok[i]) {
                #pragma unroll
                for (int j = 0; j < 8; j++) {
                    float x = bf2f(rw[i][j]);
                    pk[j] = f2bf(fmaxf((x - m8[j]) * r8[j], 0.f));
                }
            }
            int ep = (pix * 16 + grp * 8) ^ (((pix >> 2) & 1) << 3);
            *(ushort8*)&sa[ep] = pk;
        }
    }
    __syncthreads();

    // 5 K-chunks; lane's tap = 2c + (kq>>1); ch-octet = kq&1.
    const int tp = kq >> 1, off8 = (kq & 1) * 8;
    #pragma unroll
    for (int c = 0; c < 5; c++) {
        short8 bfr = *(const short8*)&wbf[(size_t)(c * COUT + ocg) * 32 + kq * 8];
        int t = 2 * c + tp; t = t > 8 ? 8 : t;   // c=4,tp=1: weights are 0
        const int ty = t / 3, tx = t - 3 * ty;
        #pragma unroll
        for (int s = 0; s < 4; s++) {
            const int mb = wm * 64 + s * 16;
            const int r = mb >> 5, cb = mb & 31;
            int px = (ty + 2 * r) * NCO + 2 * (cb + ln) + tx;
            int ep = (px * 16 + off8) ^ (((px >> 2) & 1) << 3);
            short8 afr = *(const short8*)&sa[ep];
            acc[s] = __builtin_amdgcn_mfma_f32_16x16x32_bf16(afr, bfr, acc[s], 0, 0, 0);
        }
    }

    // ---- stats partials ----
    float s1 = 0.f, s2 = 0.f;
    #pragma unroll
    for (int s = 0; s < 4; s++)
        #pragma unroll
        for (int rg = 0; rg < 4; rg++) {
            float v = acc[s][rg];
            s1 += v; s2 = fmaf(v, v, s2);
        }
    s1 += __shfl_xor(s1, 16); s2 += __shfl_xor(s2, 16);
    s1 += __shfl_xor(s1, 32); s2 += __shfl_xor(s2, 32);
    if (lane < 16) { sred[wv][lane][0] = s1; sred[wv][lane][1] = s2; }

    // ---- assemble + dense stores ----
    __syncthreads();
    const int ocl = wn * 16 + ln;
    #pragma unroll
    for (int s = 0; s < 4; s++)
        #pragma unroll
        for (int rg = 0; rg < 4; rg++) {
            const int m = wm * 64 + s * 16 + kq * 4 + rg;
            sa[m * NOCP + ocl] = f2bf(acc[s][rg]);
        }
    __syncthreads();
    ushort* ob = out + (size_t)b * HWOUT * COUT;
    for (int e = tid; e < 512; e += 256) {
        int u = e * 8;
        int lp = u >> 5, co = u & 31;
        int r = lp >> 5, c = lp & 31;
        int gp = (yc * RT + r) * WOUT + xc * CT + c;
        *(ushort8*)&ob[(size_t)gp * COUT + co] = *(const ushort8*)&sa[lp * NOCP + co];
    }
    if (tid < 32) {
        int wnn = tid >> 4, oc = tid & 15;
        float t1 = 0.f, t2 = 0.f;
        #pragma unroll
        for (int k = 0; k < 2; k++) {
            t1 += sred[wnn + k * 2][oc][0];
            t2 += sred[wnn + k * 2][oc][1];
        }
        int cix = b * COUT + wnn * 16 + oc;
        atomicAdd(&stats_out[2 * cix],     t1);
        atomicAdd(&stats_out[2 * cix + 1], t2);
    }
}

// ---------------------------------------------------------------------------
// L0: 7x7 reflect conv @512 via MFMA (unchanged).
// ---------------------------------------------------------------------------
__global__ __launch_bounds__(256, 4) void conv7x_l0(
    const float* __restrict__ inf,
    const ushort* __restrict__ wpk, const float* __restrict__ bias,
    ushort* __restrict__ out, float* __restrict__ stats_out)
{
    constexpr int W = 512, HW = 512 * 512;
    constexpr int HCOL = 70;
    constexpr int NPIXH = 980;
    constexpr int SASZ = 12288;

    __shared__ ushort sa[SASZ];
    __shared__ float sred[4][16][2];

    const int tid = threadIdx.x;
    const int lane = tid & 63, wv = tid >> 6;
    const int ln = lane & 15, kq = lane >> 4;

    int bi = xcd_swz(blockIdx.x, gridDim.x);
    const int xc = bi & 7;
    const int yr = (bi >> 3) & 63;
    const int b  = bi >> 9;
    const int y0 = yr * 8, x0 = xc * 64;

    {
        const float* p0 = inf + (size_t)b * 3 * HW;
        for (int pix = tid; pix < NPIXH; pix += 256) {
            int pr = pix / HCOL, pc = pix - pr * HCOL;
            int gy = reflect512(y0 - 3 + pr);
            int gx = reflect512(x0 - 3 + pc);
            const float* p = p0 + gy * W + gx;
            ushort4v pk;
            pk[0] = f2bf(p[0]); pk[1] = f2bf(p[HW]);
            pk[2] = f2bf(p[2 * (size_t)HW]); pk[3] = 0;
            *(ushort4v*)&sa[pix * 4] = pk;
        }
        if (tid < 16) sa[980 * 4 + tid] = 0;    // zero pad (dx=7 tail reads)
    }
    __syncthreads();

    const float b0 = bias[ln];
    f32x4 acc[8];
    #pragma unroll
    for (int s = 0; s < 8; s++) acc[s] = (f32x4){b0, b0, b0, b0};

    {
        // Wave owns rows 0..7, cols c0..c0+15. A-frag = 2 adjacent px x 4ch.
        const int c0 = wv * 16;
        const int abase = (c0 + ln + 2 * kq) * 4;
        const ushort* wp0 = wpk + ((size_t)kq * 16 + ln) * 8;
        short8 bw[7];
        #pragma unroll
        for (int ty = 0; ty < 7; ty++)
            bw[ty] = *(const short8*)(wp0 + (size_t)ty * 512);
        #pragma unroll
        for (int R = 0; R < 14; R++) {
            short8 afr = *(const short8*)&sa[abase + R * (HCOL * 4)];
            #pragma unroll
            for (int ty = 0; ty < 7; ty++) {
                const int s = R - ty;
                if (s >= 0 && s < 8)
                    acc[s] = __builtin_amdgcn_mfma_f32_16x16x32_bf16(afr, bw[ty], acc[s], 0, 0, 0);
            }
        }
    }

    // stats partials first (registers), then LDS-assembled NHWC store.
    float s1 = 0.f, s2 = 0.f;
    #pragma unroll
    for (int s = 0; s < 8; s++)
        #pragma unroll
        for (int rg = 0; rg < 4; rg++) {
            float v = acc[s][rg];
            s1 += v; s2 = fmaf(v, v, s2);
        }
    s1 += __shfl_xor(s1, 16); s2 += __shfl_xor(s2, 16);
    s1 += __shfl_xor(s1, 32); s2 += __shfl_xor(s2, 32);
    if (lane < 16) { sred[wv][lane][0] = s1; sred[wv][lane][1] = s2; }

    __syncthreads();   // A-tile reads done; reuse sa as [512][24]
    #pragma unroll
    for (int s = 0; s < 8; s++)
        #pragma unroll
        for (int rg = 0; rg < 4; rg++) {
            int m = s * 64 + wv * 16 + kq * 4 + rg;
            sa[m * 24 + ln] = f2bf(acc[s][rg]);
        }
    __syncthreads();
    ushort* ob = out + (size_t)b * HW * 16;
    for (int e = tid; e < 1024; e += 256) {
        int u = e * 8;
        int lp = u >> 4, co = u & 15;
        int gp = (y0 + (lp >> 6)) * W + x0 + (lp & 63);
        *(ushort8*)&ob[(size_t)gp * 16 + co] = *(const ushort8*)&sa[lp * 24 + co];
    }
    if (tid < 16) {
        float t1 = 0.f, t2 = 0.f;
        #pragma unroll
        for (int k = 0; k < 4; k++) { t1 += sred[k][tid][0]; t2 += sred[k][tid][1]; }
        int cix = b * 16 + tid;
        atomicAdd(&stats_out[2 * cix],     t1);
        atomicAdd(&stats_out[2 * cix + 1], t2);
    }
}

// ---------------------------------------------------------------------------
// L9: 7x7 16->3 @512 + norm + tanh + seg. 8x32 tiles, grid 4096 (r7 form).
// r10 change: issue-early staging (mfconv_l1 pattern) — all 5 guarded
// ushort8 loads + seg label issued BEFORE the mr barrier; norm+write after.
// Load latency hides under stats-load + barrier. Unclamped launch_bounds
// (r8 lesson: the (256,4) clamp forced 64 VGPR -> scratch spill disaster).
// ---------------------------------------------------------------------------
__global__ __launch_bounds__(256) void conv7x_l9(
    const ushort* __restrict__ inb16, const ushort* __restrict__ wpk,
    const float* __restrict__ bias, const float* __restrict__ stats_in,
    float invHWin, const int* __restrict__ inst, float* __restrict__ segacc)
{
    constexpr int W = 512, HW = 512 * 512;
    constexpr int HCOL = 38, STR = 16;

    __shared__ ushort sa[532 * 16 + 32];
    __shared__ float mr[16][2];
    __shared__ float segl[128];

    const int tid = threadIdx.x;
    const int lane = tid & 63, wv = tid >> 6;
    const int ln = lane & 15, kq = lane >> 4;

    int bi = xcd_swz(blockIdx.x, gridDim.x);
    const int xc = bi & 15;
    const int yr = (bi >> 4) & 63;
    const int b  = bi >> 10;
    const int y0 = yr * 8, x0 = xc * 32;

    const int h = tid & 1;
    const ushort* inb = inb16 + (size_t)b * HW * 16 + 8 * h;

    // ---- issue all staging loads + seg label up front (independent of mr)
    ushort8 rw[5];
    #pragma unroll
    for (int i = 0; i < 5; i++) {
        int pix = (tid >> 1) + i * 128;
        if (pix < 532) {
            int pr = pix / HCOL, pc = pix - pr * HCOL;
            int gy = reflect512(y0 - 3 + pr);
            int gx = reflect512(x0 - 3 + pc);
            rw[i] = *(const ushort8*)(inb + (size_t)(gy * W + gx) * 16);
        }
    }
    const int* ib = inst + ((size_t)b << 18);
    const int mylab = ib[(y0 + (tid >> 5)) * W + x0 + (tid & 31)] & 31;

    if (tid < 16) {
        int c = b * 16 + tid;
        float s1 = stats_in[2 * c], s2 = stats_in[2 * c + 1];
        float m = s1 * invHWin;
        mr[tid][0] = m;
        mr[tid][1] = rsqrtf(fmaf(s2, invHWin, -m * m) + EPS_F);
    }
    if (tid < 128) segl[tid] = 0.f;
    if (tid >= 128 && tid < 160) sa[532 * 16 + (tid - 128)] = 0;  // zero pad
    __syncthreads();                       // mr + pads + segl ready

    float r8[8], nm8[8];
    #pragma unroll
    for (int j = 0; j < 8; j++) {
        r8[j]  = mr[8 * h + j][1];
        nm8[j] = -mr[8 * h + j][0] * r8[j];
    }
    #pragma unroll
    for (int i = 0; i < 5; i++) {
        int pix = (tid >> 1) + i * 128;
        if (pix < 532) {
            union { ushort8 us; unsigned u[4]; } P;
            #pragma unroll
            for (int q2 = 0; q2 < 4; q2++) {
                float lo = fmaxf(fmaf(bf2f(rw[i][2 * q2]),     r8[2 * q2],     nm8[2 * q2]),     0.f);
                float hi = fmaxf(fmaf(bf2f(rw[i][2 * q2 + 1]), r8[2 * q2 + 1], nm8[2 * q2 + 1]), 0.f);
                P.u[q2] = cvt_pk_bf16(lo, hi);
            }
            *(ushort8*)&sa[pix * STR + 8 * h] = P.us;
        }
    }
    __syncthreads();

    const float b0 = (ln < 3) ? bias[ln] : 0.f;
    f32x4 acc[4];
    #pragma unroll
    for (int s = 0; s < 4; s++) acc[s] = (f32x4){b0, b0, b0, b0};

    // Wave (wr,wc) owns rows wr*4..+3, cols wc*16..+15.
    const int wr = wv >> 1, wc = wv & 1;
    const int abase = ((wr * 4) * HCOL + wc * 16 + ln + (kq >> 1)) * STR + (kq & 1) * 8;
    const ushort* wp9 = wpk + ((size_t)kq * 16 + ln) * 8;
    #pragma unroll
    for (int q = 0; q < 4; q++) {
        short8 bw[7];
        #pragma unroll
        for (int ty = 0; ty < 7; ty++)
            bw[ty] = *(const short8*)(wp9 + (size_t)(ty * 4 + q) * 512);
        #pragma unroll
        for (int rr = 0; rr < 10; rr++) {
            short8 afr = *(const short8*)&sa[abase + q * (2 * STR) + rr * (HCOL * STR)];
            #pragma unroll
            for (int ty = 0; ty < 7; ty++) {
                const int s = rr - ty;
                if (s >= 0 && s < 4)
                    acc[s] = __builtin_amdgcn_mfma_f32_16x16x32_bf16(afr, bw[ty], acc[s], 0, 0, 0);
            }
        }
    }

    // ---- seg epilogue: accs -> LDS [256][5] fp32, then tanh + LDS atomics.
    float* sf = (float*)sa;
    __syncthreads();   // all A-tile reads done
    if (ln < 3) {
        #pragma unroll
        for (int s = 0; s < 4; s++)
            #pragma unroll
            for (int rg = 0; rg < 4; rg++) {
                int m = (wr * 4 + s) * 32 + wc * 16 + kq * 4 + rg;
                sf[m * 5 + ln] = acc[s][rg];
            }
    }
    __syncthreads();
    atomicAdd(&segl[mylab * 4 + 0], fast_tanh(sf[tid * 5 + 0]));
    atomicAdd(&segl[mylab * 4 + 1], fast_tanh(sf[tid * 5 + 1]));
    atomicAdd(&segl[mylab * 4 + 2], fast_tanh(sf[tid * 5 + 2]));
    atomicAdd(&segl[mylab * 4 + 3], 1.f);
    __syncthreads();
    if (tid < 128) {
        float v = segl[tid];
        if (v != 0.f)
            atomicAdd(&segacc[(blockIdx.x & 7) * 128 + tid], v);  // 8 shards
    }
}

// ---------------------------------------------------------------------------
// Segment finalize (reduce 8 shards) + scatter (vectorized: 4 px/thread).
// ---------------------------------------------------------------------------
#define HW9 262144
__global__ void seg_final(const float* __restrict__ acc, float* __restrict__ means)
{
    int i = threadIdx.x;
    if (i < 96) {
        int s = i / 3, c = i - s * 3;
        float num = 0.f, den = 0.f;
        #pragma unroll
        for (int k = 0; k < 8; k++) {
            num += acc[k * 128 + s * 4 + c];
            den += acc[k * 128 + s * 4 + 3];
        }
        means[i] = num / fmaxf(den, 1.f);
    }
}

__global__ __launch_bounds__(256) void seg_scatter(
    const int* __restrict__ inst, const float* __restrict__ means,
    float* __restrict__ out)
{
    int p4 = blockIdx.x * 256 + threadIdx.x;   // 4-pixel unit
    int b  = p4 >> 16;                          // 65536 units per batch
    int r4 = (p4 & 65535) * 4;
    const int4v labs = *(const int4v*)(inst + ((size_t)b << 18) + r4);
    float* ob = out + (size_t)b * 3 * HW9 + r4;
    f32x4 o0, o1, o2;
    #pragma unroll
    for (int j = 0; j < 4; j++) {
        int l3 = (labs[j] & 31) * 3;
        o0[j] = means[l3]; o1[j] = means[l3 + 1]; o2[j] = means[l3 + 2];
    }
    *(f32x4*)(ob)           = o0;
    *(f32x4*)(ob + HW9)     = o1;
    *(f32x4*)(ob + 2 * HW9) = o2;
}

// ---------------------------------------------------------------------------
// Launch.
// ---------------------------------------------------------------------------
extern "C" void kernel_launch(void* const* d_in, const int* in_sizes, int n_in,
                              void* d_out, int out_size, void* d_ws, size_t ws_size,
                              hipStream_t stream)
{
    const float* x_in = (const float*)d_in[0];
    const int*   inst = (const int*)d_in[1];
    const float* W_[10];
    const float* Bs[10];
    for (int i = 0; i < 10; i++) {
        W_[i] = (const float*)d_in[2 + 2 * i];
        Bs[i] = (const float*)d_in[3 + 2 * i];
    }
    float* out = (float*)d_out;

    // NHWC bf16 activation ping-pong + fp32 stats + bf16 weights.
    ushort* Ab  = (ushort*)d_ws;            // 16,777,216 el
    ushort* Bb2 = Ab + (size_t)16777216;    //  8,388,608 el
    float*  st  = (float*)(Bb2 + (size_t)8388608);
    const int coff[9] = {0, 128, 384, 896, 1920, 3968, 4992, 5504, 5760};
    float* s_[9];
    for (int i = 0; i < 9; i++) s_[i] = st + coff[i];
    float* segacc = st + 5888;              // 8 shards x 128 = 1024 floats
    float* means  = st + 6912;              // 96 floats
    ushort* wb = (ushort*)(st + 8192);
    const size_t OW1 = 0, OW2 = 9216, OW3 = 27648, OW4 = 101376,
                 OW5 = 396288, OW6 = 691200, OW7 = 764928, OW8 = 783360;
    ushort* wb0 = wb + 790000;
    ushort* wb9 = wb0 + 6656;   // L9 pack: 28 chunks x 512 = 14336 ushorts

    hipMemsetAsync(st, 0, 6912 * sizeof(float), stream);

    WprepArgs wa;
    for (int i = 0; i < 10; i++) wa.w[i] = W_[i];
    wa.d[0] = wb0;
    wa.d[1] = wb + OW1; wa.d[2] = wb + OW2; wa.d[3] = wb + OW3; wa.d[4] = wb + OW4;
    wa.d[5] = wb + OW5; wa.d[6] = wb + OW6; wa.d[7] = wb + OW7; wa.d[8] = wb + OW8;
    wa.d[9] = wb9;
    wprep_all<<<dim3(3132), dim3(256), 0, stream>>>(wa);

    // L0: 7x7 3->16 @512, fp32 NCHW in -> NHWC bf16 out + stats. grid 2048.
    conv7x_l0<<<dim3(2048), dim3(256), 0, stream>>>(
        x_in, wb0, Bs[0], Ab, s_[0]);

    // L1: conv 16->32 @512->256 (dedicated kernel, stride-16 A-tile). grid 2048.
    mfconv_l1<<<dim3(2048), dim3(256), 18720, stream>>>(
        Ab, wb + OW1, Bs[1], Bb2, s_[0], 1.f / 262144.f, s_[1]);

    // L2: conv 32->64 @256->128. grid 1024.
    mfconv<32, 64, 256, 0, 2, 4, 4, 32><<<dim3(1024), dim3(256), 42120, stream>>>(
        Bb2, wb + OW2, Bs[2], Ab, s_[1], 1.f / 65536.f, s_[2]);

    // L3: conv 64->128 @128->64. grid 512.
    mfconv<64, 128, 128, 0, 2, 4, 4, 32><<<dim3(512), dim3(256), 42120, stream>>>(
        Ab, wb + OW3, Bs[3], Bb2, s_[2], 1.f / 16384.f, s_[3]);

    // L4: conv 128->256 @64->32. grid 512.
    mfconv<128, 256, 64, 0, 2, 2, 2, 32><<<dim3(512), dim3(256), 23400, stream>>>(
        Bb2, wb + OW4, Bs[4], Ab, s_[3], 1.f / 4096.f, s_[4]);

    // L5: deconv 256->128 @32->64. grid 512. LDS 12288 (epilogue-sized).
    mfconv<256, 128, 32, 1, 1, 1, 2, 32><<<dim3(512), dim3(256), 12288, stream>>>(
        Ab, wb + OW5, Bs[5], Bb2, s_[4], 1.f / 1024.f, s_[5]);

    // L6: deconv 128->64 @64->128. grid 512. LDS 20480.
    mfconv<128, 64, 64, 1, 2, 2, 2, 32><<<dim3(512), dim3(256), 20480, stream>>>(
        Bb2, wb + OW6, Bs[6], Ab, s_[5], 1.f / 4096.f, s_[6]);

    // L7: deconv 64->32 @128->256. grid 1024. LDS 20480.
    mfconv<64, 32, 128, 1, 2, 2, 2, 32><<<dim3(1024), dim3(256), 20480, stream>>>(
        Ab, wb + OW7, Bs[7], Bb2, s_[6], 1.f / 16384.f, s_[7]);

    // L8: deconv 32->16 @256->512. M=128, grid 2048. LDS 24576.
    mfconv<32, 16, 256, 1, 1, 2, 2, 64><<<dim3(2048), dim3(256), 24576, stream>>>(
        Bb2, wb + OW8, Bs[8], Ab, s_[7], 1.f / 65536.f, s_[8]);

    // L9: 7x7 16->3 @512 + norm + tanh + seg. 8x32 tiles, grid 4096.
    conv7x_l9<<<dim3(4096), dim3(256), 0, stream>>>(
        Ab, wb9, Bs[9], s_[8], 1.f / 262144.f, inst, segacc);

    seg_final<<<dim3(1), dim3(96), 0, stream>>>(segacc, means);
    seg_scatter<<<dim3(1024), dim3(256), 0, stream>>>(inst, means, out);
}